// Round 2
// baseline (617.256 us; speedup 1.0000x reference)
//
#include <hip/hip_runtime.h>
#include <hip/hip_bf16.h>
#include <math.h>

#define D_IN 1024
#define D_HID 256
#define D_CLS 128
#define N_CLASSES 4
#define N_INST 50000

#define NPAD 50176                   // 392*128
#define G1 (NPAD / 64)               // 784 stage1 blocks (64 rows each)
#define RG2 128
#define GB (NPAD / RG2)              // 392
#define PSTR 258
#define NEG_BIG (-1e30f)

// ---- fallback-path geometry (R3, proven) ----
#define ROWS 64
#define NBLK ((N_INST + ROWS - 1) / ROWS)   // 782
#define NB2 64
#define CHUNK ((NBLK + NB2 - 1) / NB2)      // 13

// ---- workspace layout (bytes) ----
#define WS_W1T   0u
#define WS_WVT   524288u
#define WS_WAT   655360u
#define WS_WBT   786432u
#define WS_CNT   917504u
#define WS_P1    917760u                               // 392*258*4 = 404544 -> ends 1322304
#define WS_H     1322304u                              // NPAD*256*2 = 25690112
#define WS_NEED2 ((size_t)WS_H + 25690112u)            // ~27 MB
// fallback offsets
#define WS_P1F   917504u
#define WS_P2F   1724800u

typedef __attribute__((ext_vector_type(8))) short bf16x8;
typedef __attribute__((ext_vector_type(4))) float f32x4;

__device__ __forceinline__ short f2bf(float x) {
    __hip_bfloat16 h = __float2bfloat16(x);
    return *reinterpret_cast<short*>(&h);
}
__device__ __forceinline__ float fast_tanh(float x) {
    float e = __expf(2.f * x);
    return 1.f - 2.f * __builtin_amdgcn_rcpf(e + 1.f);
}
__device__ __forceinline__ float fast_sigmoid(float x) {
    return __builtin_amdgcn_rcpf(1.f + __expf(-x));
}
__device__ __forceinline__ bf16x8 cvt8(float4 a, float4 b) {
    bf16x8 r;
    r[0] = f2bf(a.x); r[1] = f2bf(a.y); r[2] = f2bf(a.z); r[3] = f2bf(a.w);
    r[4] = f2bf(b.x); r[5] = f2bf(b.y); r[6] = f2bf(b.z); r[7] = f2bf(b.w);
    return r;
}
__device__ __forceinline__ bf16x8 load_cvt8(const float* __restrict__ p) {
    return cvt8(*(const float4*)p, *(const float4*)(p + 4));
}

// ================= weight convert + transpose (fp32 [K][256] -> bf16 [256][K]) =================
__global__ void convert_weights(const float* __restrict__ w1, const float* __restrict__ wv,
                                const float* __restrict__ wa, const float* __restrict__ wb,
                                __hip_bfloat16* __restrict__ w1t, __hip_bfloat16* __restrict__ wvt,
                                __hip_bfloat16* __restrict__ wat, __hip_bfloat16* __restrict__ wbt) {
    __shared__ __hip_bfloat16 T[64][68];
    int b = blockIdx.x, tid = threadIdx.x;
    const float* src; __hip_bfloat16* dst; int K, tr, tc;
    if (b < 64) { src = w1; dst = w1t; K = D_IN; tr = b >> 2; tc = b & 3; }
    else {
        int m = (b - 64) >> 4, t = (b - 64) & 15;
        src = (m == 0) ? wv : (m == 1) ? wa : wb;
        dst = (m == 0) ? wvt : (m == 1) ? wat : wbt;
        K = D_HID; tr = t >> 2; tc = t & 3;
    }
    int k0 = tr * 64, n0 = tc * 64;
#pragma unroll
    for (int p = 0; p < 4; p++) {
        int lin = p * 256 + tid;
        int r = lin >> 4;
        int c4 = (lin & 15) << 2;
        float4 v = *(const float4*)(src + (size_t)(k0 + r) * D_HID + n0 + c4);
        T[c4 + 0][r] = __float2bfloat16(v.x);
        T[c4 + 1][r] = __float2bfloat16(v.y);
        T[c4 + 2][r] = __float2bfloat16(v.z);
        T[c4 + 3][r] = __float2bfloat16(v.w);
    }
    __syncthreads();
#pragma unroll
    for (int p = 0; p < 4; p++) {
        int lin = p * 256 + tid;
        int n = lin >> 4;
        int kq = (lin & 15) << 2;
        ushort4 o;
        o.x = *(unsigned short*)&T[n][kq + 0];
        o.y = *(unsigned short*)&T[n][kq + 1];
        o.z = *(unsigned short*)&T[n][kq + 2];
        o.w = *(unsigned short*)&T[n][kq + 3];
        *(ushort4*)(dst + (size_t)(n0 + n) * K + k0 + kq) = o;
    }
}

// ================= stage 1 (v2: barrier-free, direct global->reg X loads) =================
// h = relu(X @ W1 + b1). 64 rows x 256 cols per block, 4 waves (each 64 rows x 64 cols).
// A-fragments are 8 consecutive K elems of one row -> loadable straight from row-major X
// with inline fp32->bf16 convert; no LDS, no __syncthreads in the K loop, so the compiler
// is free to software-pipeline loads across K-steps (no vmcnt(0) barrier drain).
// h written in the MFMA-tiled layout consumed by stage2 (identical to previous version):
//   h[((t128*8 + (col>>5))*4 + ((col>>3)&3))*1024 + row128*8 + (col&7)]
__global__ __launch_bounds__(256, 3) void mcat_stage1g(const float* __restrict__ xp,
                                                       const __hip_bfloat16* __restrict__ w1t,
                                                       const float* __restrict__ b1,
                                                       __hip_bfloat16* __restrict__ hout) {
    const int tid  = threadIdx.x;
    const int wave = tid >> 6;
    const int lane = tid & 63;
    const int quad = lane >> 4;
    const int l16  = lane & 15;
    const int row0 = blockIdx.x * 64;
    const int t128 = blockIdx.x >> 1;
    const int rhalf = blockIdx.x & 1;

    // per-lane X row pointers (A-frag: row = rt*16 + l16, k-offset = quad*8)
    const float* xb[4];
#pragma unroll
    for (int rt = 0; rt < 4; rt++) {
        int r = row0 + rt * 16 + l16;
        if (r > N_INST - 1) r = N_INST - 1;   // clamp: valid memory, masked in stage2
        xb[rt] = xp + (size_t)r * D_IN + quad * 8;
    }
    // per-lane W row pointers (B-frag: col = wave*64 + ct*16 + l16, k-offset = quad*8)
    const __hip_bfloat16* wb[4];
#pragma unroll
    for (int ct = 0; ct < 4; ct++)
        wb[ct] = w1t + (size_t)(wave * 64 + ct * 16 + l16) * D_IN + quad * 8;

    f32x4 acc[4][4];
    f32x4 zero = {0.f, 0.f, 0.f, 0.f};
#pragma unroll
    for (int i = 0; i < 4; i++)
#pragma unroll
        for (int j = 0; j < 4; j++) acc[i][j] = zero;

    // barrier-free K loop: 32 steps of K=32; unroll 4 so ~4 steps of loads stay in flight
#pragma unroll 4
    for (int kc = 0; kc < D_IN; kc += 32) {
        bf16x8 bfv[4];
#pragma unroll
        for (int ct = 0; ct < 4; ct++)
            bfv[ct] = *(const bf16x8*)(wb[ct] + kc);
        bf16x8 af[4];
#pragma unroll
        for (int rt = 0; rt < 4; rt++)
            af[rt] = load_cvt8(xb[rt] + kc);
#pragma unroll
        for (int ct = 0; ct < 4; ct++)
#pragma unroll
            for (int rt = 0; rt < 4; rt++)
                acc[rt][ct] = __builtin_amdgcn_mfma_f32_16x16x32_bf16(af[rt], bfv[ct], acc[rt][ct], 0, 0, 0);
    }

    // epilogue: bias+relu -> tiled h (identical layout to previous stage1)
#pragma unroll
    for (int ct = 0; ct < 4; ct++) {
        const int col = wave * 64 + ct * 16 + l16;
        const float bias = b1[col];
        __hip_bfloat16* hb = hout + (((size_t)(t128 * 8 + (col >> 5)) * 4 + ((col >> 3) & 3)) << 10)
                                  + rhalf * 512 + (col & 7);
#pragma unroll
        for (int rt = 0; rt < 4; rt++)
#pragma unroll
            for (int r = 0; r < 4; r++) {
                int row = rt * 16 + quad * 4 + r;
                hb[row * 8] = __float2bfloat16(fmaxf(acc[rt][ct][r] + bias, 0.f));
            }
    }
}

// ================= stage 2: v/a/b GEMMs + gated attention + partials + fused finalize =================
__global__ __launch_bounds__(512, 1) void mcat_stage2(const __hip_bfloat16* __restrict__ h,
                          const __hip_bfloat16* __restrict__ wvt, const float* __restrict__ bv,
                          const __hip_bfloat16* __restrict__ wat, const float* __restrict__ ba,
                          const __hip_bfloat16* __restrict__ wbt, const float* __restrict__ bb,
                          const float* __restrict__ acw, const float* __restrict__ acb,
                          float* __restrict__ p1, unsigned int* __restrict__ counter,
                          const float* __restrict__ c1w, const float* __restrict__ c1b,
                          const float* __restrict__ c2w, const float* __restrict__ c2b,
                          float* __restrict__ out) {
    __shared__ __hip_bfloat16 Vs[RG2][264];
    __shared__ float Apart[8][RG2];
    __shared__ float ExpW[RG2];
    __shared__ float smx[4];
    __shared__ float scb[GB];
    __shared__ float pooled[D_HID];
    __shared__ float r1v[D_CLS];

    const int tid  = threadIdx.x;
    const int wave = tid >> 6;
    const int lane = tid & 63;
    const int quad = lane >> 4;
    const int l16  = lane & 15;
    const int cb   = wave * 32;
    const int row0 = blockIdx.x * RG2;

    f32x4 acc[8][2];
    f32x4 zero = {0.f, 0.f, 0.f, 0.f};

    // ---- v = h @ Wv + bv : A direct from tiled h ----
    const __hip_bfloat16* hb = h + (size_t)blockIdx.x * 32768 + quad * 1024 + l16 * 8;
#pragma unroll
    for (int i = 0; i < 8; i++) { acc[i][0] = zero; acc[i][1] = zero; }
    {
        const __hip_bfloat16* w0 = wvt + (size_t)(cb + l16) * D_HID + quad * 8;
        const __hip_bfloat16* w1p = w0 + 16 * D_HID;
#pragma unroll
        for (int ks = 0; ks < 8; ks++) {
            bf16x8 b0 = *(const bf16x8*)(w0 + ks * 32);
            bf16x8 b1f = *(const bf16x8*)(w1p + ks * 32);
#pragma unroll
            for (int rt = 0; rt < 8; rt++) {
                bf16x8 af = *(const bf16x8*)(hb + ks * 4096 + rt * 128);
                acc[rt][0] = __builtin_amdgcn_mfma_f32_16x16x32_bf16(af, b0, acc[rt][0], 0, 0, 0);
                acc[rt][1] = __builtin_amdgcn_mfma_f32_16x16x32_bf16(af, b1f, acc[rt][1], 0, 0, 0);
            }
        }
    }
#pragma unroll
    for (int ct = 0; ct < 2; ct++) {
        int col = cb + ct * 16 + l16;
        float bias = bv[col];
#pragma unroll
        for (int rt = 0; rt < 8; rt++)
#pragma unroll
            for (int r = 0; r < 4; r++)
                Vs[rt * 16 + quad * 4 + r][col] = __float2bfloat16(acc[rt][ct][r] + bias);
    }
    __syncthreads();

    // ---- a = tanh(v @ Wa + ba), kept in regs ----
    float a_reg[8][2][4];
#pragma unroll
    for (int i = 0; i < 8; i++) { acc[i][0] = zero; acc[i][1] = zero; }
    {
        const __hip_bfloat16* w0 = wat + (size_t)(cb + l16) * D_HID + quad * 8;
        const __hip_bfloat16* w1p = w0 + 16 * D_HID;
#pragma unroll
        for (int ks = 0; ks < 8; ks++) {
            bf16x8 b0 = *(const bf16x8*)(w0 + ks * 32);
            bf16x8 b1f = *(const bf16x8*)(w1p + ks * 32);
#pragma unroll
            for (int rt = 0; rt < 8; rt++) {
                bf16x8 af = *(const bf16x8*)&Vs[rt * 16 + l16][ks * 32 + quad * 8];
                acc[rt][0] = __builtin_amdgcn_mfma_f32_16x16x32_bf16(af, b0, acc[rt][0], 0, 0, 0);
                acc[rt][1] = __builtin_amdgcn_mfma_f32_16x16x32_bf16(af, b1f, acc[rt][1], 0, 0, 0);
            }
        }
    }
#pragma unroll
    for (int ct = 0; ct < 2; ct++) {
        float bias = ba[cb + ct * 16 + l16];
#pragma unroll
        for (int rt = 0; rt < 8; rt++)
#pragma unroll
            for (int r = 0; r < 4; r++)
                a_reg[rt][ct][r] = fast_tanh(acc[rt][ct][r] + bias);
    }

    // ---- b-gate GEMM + fold attention dot ----
#pragma unroll
    for (int i = 0; i < 8; i++) { acc[i][0] = zero; acc[i][1] = zero; }
    {
        const __hip_bfloat16* w0 = wbt + (size_t)(cb + l16) * D_HID + quad * 8;
        const __hip_bfloat16* w1p = w0 + 16 * D_HID;
#pragma unroll
        for (int ks = 0; ks < 8; ks++) {
            bf16x8 b0 = *(const bf16x8*)(w0 + ks * 32);
            bf16x8 b1f = *(const bf16x8*)(w1p + ks * 32);
#pragma unroll
            for (int rt = 0; rt < 8; rt++) {
                bf16x8 af = *(const bf16x8*)&Vs[rt * 16 + l16][ks * 32 + quad * 8];
                acc[rt][0] = __builtin_amdgcn_mfma_f32_16x16x32_bf16(af, b0, acc[rt][0], 0, 0, 0);
                acc[rt][1] = __builtin_amdgcn_mfma_f32_16x16x32_bf16(af, b1f, acc[rt][1], 0, 0, 0);
            }
        }
    }
    {
        float acw0 = acw[cb + l16], acw1 = acw[cb + 16 + l16];
        float bb0 = bb[cb + l16],  bb1 = bb[cb + 16 + l16];
        float sp[8][4];
#pragma unroll
        for (int rt = 0; rt < 8; rt++)
#pragma unroll
            for (int r = 0; r < 4; r++) {
                float g0 = a_reg[rt][0][r] * fast_sigmoid(acc[rt][0][r] + bb0);
                float g1 = a_reg[rt][1][r] * fast_sigmoid(acc[rt][1][r] + bb1);
                sp[rt][r] = g0 * acw0 + g1 * acw1;
            }
#pragma unroll
        for (int off = 1; off < 16; off <<= 1)
#pragma unroll
            for (int rt = 0; rt < 8; rt++)
#pragma unroll
                for (int r = 0; r < 4; r++)
                    sp[rt][r] += __shfl_xor(sp[rt][r], off, 16);
        if (l16 == 0) {
#pragma unroll
            for (int rt = 0; rt < 8; rt++)
#pragma unroll
                for (int r = 0; r < 4; r++)
                    Apart[wave][rt * 16 + quad * 4 + r] = sp[rt][r];
        }
    }
    __syncthreads();

    // ---- block-local online softmax over 128 rows ----
    if (tid < 64) {
        float A0 = acb[0], A1 = acb[0];
#pragma unroll
        for (int w = 0; w < 8; w++) { A0 += Apart[w][tid]; A1 += Apart[w][tid + 64]; }
        bool v0 = (row0 + tid) < N_INST;
        bool v1 = (row0 + 64 + tid) < N_INST;
        if (!v0) A0 = NEG_BIG;
        if (!v1) A1 = NEG_BIG;
        float m = fmaxf(A0, A1);
#pragma unroll
        for (int off = 32; off > 0; off >>= 1) m = fmaxf(m, __shfl_xor(m, off));
        float e0 = v0 ? __expf(A0 - m) : 0.f;
        float e1 = v1 ? __expf(A1 - m) : 0.f;
        ExpW[tid] = e0; ExpW[tid + 64] = e1;
        float ssum = e0 + e1;
#pragma unroll
        for (int off = 32; off > 0; off >>= 1) ssum += __shfl_xor(ssum, off);
        if (tid == 0) {
            p1[(size_t)blockIdx.x * PSTR + 0] = m;
            p1[(size_t)blockIdx.x * PSTR + 1] = ssum;
        }
    }
    __syncthreads();
    if (tid < 256) {
        float p = 0.f;
#pragma unroll 8
        for (int n = 0; n < RG2; n++)
            p += ExpW[n] * __bfloat162float(Vs[n][tid]);
        p1[(size_t)blockIdx.x * PSTR + 2 + tid] = p;
    }

    // ---- last-block finalize (atomic ticket) ----
    __syncthreads();
    if (tid == 0) {
        __threadfence();
        unsigned int old = __hip_atomic_fetch_add(counter, 1u, __ATOMIC_ACQ_REL, __HIP_MEMORY_SCOPE_AGENT);
        smx[3] = (old == GB - 1) ? 1.f : 0.f;
    }
    __syncthreads();
    if (smx[3] == 0.f) return;
    __threadfence();

    {
        float mloc = NEG_BIG;
        for (int b = tid; b < GB; b += 512) mloc = fmaxf(mloc, p1[(size_t)b * PSTR]);
#pragma unroll
        for (int off = 32; off > 0; off >>= 1) mloc = fmaxf(mloc, __shfl_xor(mloc, off));
        if (lane == 0) ExpW[wave] = mloc;
    }
    __syncthreads();
    if (tid == 0) {
        float M = NEG_BIG;
#pragma unroll
        for (int w = 0; w < 8; w++) M = fmaxf(M, ExpW[w]);
        smx[0] = M;
    }
    __syncthreads();
    {
        float M = smx[0];
        float sl = 0.f;
        for (int b = tid; b < GB; b += 512) {
            float s = __expf(p1[(size_t)b * PSTR] - M);
            scb[b] = s;
            sl += s * p1[(size_t)b * PSTR + 1];
        }
#pragma unroll
        for (int off = 32; off > 0; off >>= 1) sl += __shfl_xor(sl, off);
        if (lane == 0) ExpW[8 + wave] = sl;
    }
    __syncthreads();
    if (tid == 0) {
        float S = 0.f;
#pragma unroll
        for (int w = 0; w < 8; w++) S += ExpW[8 + w];
        smx[1] = S;
    }
    __syncthreads();
    if (tid < 256) {
        float p = 0.f;
        for (int b = 0; b < GB; b++)
            p += scb[b] * p1[(size_t)b * PSTR + 2 + tid];
        pooled[tid] = p / smx[1];
    }
    __syncthreads();
    if (tid < D_CLS) {
        float a2 = c1b[tid];
#pragma unroll 8
        for (int d = 0; d < D_HID; d++)
            a2 += pooled[d] * c1w[(size_t)d * D_CLS + tid];
        r1v[tid] = fmaxf(a2, 0.f);
    }
    __syncthreads();
    if (tid < N_CLASSES) {
        float a2 = c2b[tid];
#pragma unroll 8
        for (int j = 0; j < D_CLS; j++)
            a2 += r1v[j] * c2w[(size_t)j * N_CLASSES + tid];
        out[tid] = a2;
    }
}

// ===================== fallback path (R3, proven) =====================
__device__ __forceinline__ void gemm256_w8(const __hip_bfloat16 (*S)[264],
                                           const __hip_bfloat16* __restrict__ Wt,
                                           int colbase, int quad, int l16, f32x4 acc[4][2]) {
    f32x4 zero = {0.f, 0.f, 0.f, 0.f};
#pragma unroll
    for (int i = 0; i < 4; i++) { acc[i][0] = zero; acc[i][1] = zero; }
    const __hip_bfloat16* w0 = Wt + (size_t)(colbase + l16) * D_HID + quad * 8;
    const __hip_bfloat16* w1 = w0 + 16 * D_HID;
#pragma unroll
    for (int ks = 0; ks < 8; ks++) {
        bf16x8 af[4];
#pragma unroll
        for (int rt = 0; rt < 4; rt++)
            af[rt] = *(const bf16x8*)&S[rt * 16 + l16][ks * 32 + quad * 8];
        bf16x8 b0 = *(const bf16x8*)(w0 + ks * 32);
        bf16x8 b1 = *(const bf16x8*)(w1 + ks * 32);
#pragma unroll
        for (int rt = 0; rt < 4; rt++) {
            acc[rt][0] = __builtin_amdgcn_mfma_f32_16x16x32_bf16(af[rt], b0, acc[rt][0], 0, 0, 0);
            acc[rt][1] = __builtin_amdgcn_mfma_f32_16x16x32_bf16(af[rt], b1, acc[rt][1], 0, 0, 0);
        }
    }
}

__global__ __launch_bounds__(512, 4) void mcat_mainF(const float* __restrict__ xsrc,
                          const __hip_bfloat16* __restrict__ w1t, const float* __restrict__ b1,
                          const __hip_bfloat16* __restrict__ wvt, const float* __restrict__ bv,
                          const __hip_bfloat16* __restrict__ wat, const float* __restrict__ ba,
                          const __hip_bfloat16* __restrict__ wbt, const float* __restrict__ bb,
                          const float* __restrict__ acw, const float* __restrict__ acb,
                          float* __restrict__ partials) {
    __shared__ __hip_bfloat16 Hs[ROWS][264];
    __shared__ __hip_bfloat16 Vs[ROWS][264];
    __shared__ float Apart[8][ROWS];
    __shared__ float ExpW[ROWS];
    const int tid  = threadIdx.x;
    const int wave = tid >> 6;
    const int lane = tid & 63;
    const int quad = lane >> 4;
    const int l16  = lane & 15;
    const int colbase = wave * 32;
    const int row0 = blockIdx.x * ROWS;
    f32x4 acc[4][2];
    f32x4 zero = {0.f, 0.f, 0.f, 0.f};
#pragma unroll
    for (int i = 0; i < 4; i++) { acc[i][0] = zero; acc[i][1] = zero; }
    const float* xf_base[4];
#pragma unroll
    for (int rt = 0; rt < 4; rt++) {
        int r = row0 + rt * 16 + l16;
        if (r > N_INST - 1) r = N_INST - 1;
        xf_base[rt] = xsrc + (size_t)r * D_IN + quad * 8;
    }
    const __hip_bfloat16* wb0 = w1t + (size_t)(colbase + l16) * D_IN + quad * 8;
    const __hip_bfloat16* wb1 = wb0 + 16 * D_IN;
    for (int kc = 0; kc < D_IN; kc += 32) {
        bf16x8 af[4];
#pragma unroll
        for (int rt = 0; rt < 4; rt++) af[rt] = load_cvt8(xf_base[rt] + kc);
        bf16x8 b0 = *(const bf16x8*)(wb0 + kc);
        bf16x8 b1 = *(const bf16x8*)(wb1 + kc);
#pragma unroll
        for (int rt = 0; rt < 4; rt++) {
            acc[rt][0] = __builtin_amdgcn_mfma_f32_16x16x32_bf16(af[rt], b0, acc[rt][0], 0, 0, 0);
            acc[rt][1] = __builtin_amdgcn_mfma_f32_16x16x32_bf16(af[rt], b1, acc[rt][1], 0, 0, 0);
        }
    }
#pragma unroll
    for (int ct = 0; ct < 2; ct++) {
        int col = colbase + ct * 16 + l16;
        float bias = b1[col];
#pragma unroll
        for (int rt = 0; rt < 4; rt++)
#pragma unroll
            for (int r = 0; r < 4; r++)
                Hs[rt * 16 + quad * 4 + r][col] = __float2bfloat16(fmaxf(acc[rt][ct][r] + bias, 0.f));
    }
    __syncthreads();
    gemm256_w8(Hs, wvt, colbase, quad, l16, acc);
#pragma unroll
    for (int ct = 0; ct < 2; ct++) {
        int col = colbase + ct * 16 + l16;
        float bias = bv[col];
#pragma unroll
        for (int rt = 0; rt < 4; rt++)
#pragma unroll
            for (int r = 0; r < 4; r++)
                Vs[rt * 16 + quad * 4 + r][col] = __float2bfloat16(acc[rt][ct][r] + bias);
    }
    __syncthreads();
    float a_reg[4][2][4];
    gemm256_w8(Vs, wat, colbase, quad, l16, acc);
#pragma unroll
    for (int ct = 0; ct < 2; ct++) {
        float bias = ba[colbase + ct * 16 + l16];
#pragma unroll
        for (int rt = 0; rt < 4; rt++)
#pragma unroll
            for (int r = 0; r < 4; r++)
                a_reg[rt][ct][r] = fast_tanh(acc[rt][ct][r] + bias);
    }
    gemm256_w8(Vs, wbt, colbase, quad, l16, acc);
    {
        float acw0 = acw[colbase + l16];
        float acw1 = acw[colbase + 16 + l16];
        float bias0 = bb[colbase + l16];
        float bias1 = bb[colbase + 16 + l16];
        float sp[4][4];
#pragma unroll
        for (int rt = 0; rt < 4; rt++)
#pragma unroll
            for (int r = 0; r < 4; r++) {
                float g0 = a_reg[rt][0][r] * fast_sigmoid(acc[rt][0][r] + bias0);
                float g1 = a_reg[rt][1][r] * fast_sigmoid(acc[rt][1][r] + bias1);
                sp[rt][r] = g0 * acw0 + g1 * acw1;
            }
#pragma unroll
        for (int off = 1; off < 16; off <<= 1)
#pragma unroll
            for (int rt = 0; rt < 4; rt++)
#pragma unroll
                for (int r = 0; r < 4; r++)
                    sp[rt][r] += __shfl_xor(sp[rt][r], off, 16);
        if (l16 == 0) {
#pragma unroll
            for (int rt = 0; rt < 4; rt++)
#pragma unroll
                for (int r = 0; r < 4; r++)
                    Apart[wave][rt * 16 + quad * 4 + r] = sp[rt][r];
        }
    }
    __syncthreads();
    if (tid < 64) {
        bool valid = (row0 + tid) < N_INST;
        float A = acb[0];
#pragma unroll
        for (int w = 0; w < 8; w++) A += Apart[w][tid];
        if (!valid) A = NEG_BIG;
        float m = A;
#pragma unroll
        for (int off = 32; off > 0; off >>= 1) m = fmaxf(m, __shfl_xor(m, off));
        float e = valid ? __expf(A - m) : 0.f;
        ExpW[tid] = e;
        float ssum = e;
#pragma unroll
        for (int off = 32; off > 0; off >>= 1) ssum += __shfl_xor(ssum, off);
        if (tid == 0) {
            partials[(size_t)blockIdx.x * PSTR + 0] = m;
            partials[(size_t)blockIdx.x * PSTR + 1] = ssum;
        }
    }
    __syncthreads();
    if (tid < 256) {
        float p = 0.f;
#pragma unroll 8
        for (int n = 0; n < 64; n++)
            p += ExpW[n] * __bfloat162float(Vs[n][tid]);
        partials[(size_t)blockIdx.x * PSTR + 2 + tid] = p;
    }
}

__global__ void mcat_fin_a(const float* __restrict__ p1, float* __restrict__ p2) {
    __shared__ float sm[1];
    int g = blockIdx.x, tid = threadIdx.x;
    int lo = g * CHUNK;
    int hi = lo + CHUNK; if (hi > NBLK) hi = NBLK;
    if (tid < 64) {
        float m = NEG_BIG;
        if (lo + tid < hi) m = p1[(size_t)(lo + tid) * PSTR];
#pragma unroll
        for (int off = 32; off > 0; off >>= 1) m = fmaxf(m, __shfl_xor(m, off));
        if (tid == 0) sm[0] = m;
    }
    __syncthreads();
    float M = sm[0];
    float p = 0.f, sacc = 0.f;
    for (int b = lo; b < hi; b++) {
        float sc = __expf(p1[(size_t)b * PSTR] - M);
        sacc += sc * p1[(size_t)b * PSTR + 1];
        p += sc * p1[(size_t)b * PSTR + 2 + tid];
    }
    if (tid == 0) {
        p2[(size_t)g * PSTR + 0] = M;
        p2[(size_t)g * PSTR + 1] = sacc;
    }
    p2[(size_t)g * PSTR + 2 + tid] = p;
}

__global__ void mcat_fin_b(const float* __restrict__ p2,
                           const float* __restrict__ c1w, const float* __restrict__ c1b,
                           const float* __restrict__ c2w, const float* __restrict__ c2b,
                           float* __restrict__ out) {
    __shared__ float sm[2];
    __shared__ float sc[NB2];
    __shared__ float pooled[D_HID];
    __shared__ float r1[D_CLS];
    int tid = threadIdx.x;
    if (tid < 64) {
        float m = p2[(size_t)tid * PSTR];
#pragma unroll
        for (int off = 32; off > 0; off >>= 1) m = fmaxf(m, __shfl_xor(m, off));
        if (tid == 0) sm[0] = m;
    }
    __syncthreads();
    float M = sm[0];
    if (tid < 64) {
        float s = __expf(p2[(size_t)tid * PSTR] - M);
        sc[tid] = s;
        float Ssum = s * p2[(size_t)tid * PSTR + 1];
#pragma unroll
        for (int off = 32; off > 0; off >>= 1) Ssum += __shfl_xor(Ssum, off);
        if (tid == 0) sm[1] = Ssum;
    }
    __syncthreads();
    float S = sm[1];
    float p = 0.f;
#pragma unroll 8
    for (int b = 0; b < NB2; b++)
        p += sc[b] * p2[(size_t)b * PSTR + 2 + tid];
    pooled[tid] = p / S;
    __syncthreads();
    if (tid < D_CLS) {
        float acc = c1b[tid];
#pragma unroll 8
        for (int d = 0; d < D_HID; d++)
            acc += pooled[d] * c1w[(size_t)d * D_CLS + tid];
        r1[tid] = fmaxf(acc, 0.f);
    }
    __syncthreads();
    if (tid < N_CLASSES) {
        float acc = c2b[tid];
#pragma unroll 8
        for (int j = 0; j < D_CLS; j++)
            acc += r1[j] * c2w[(size_t)j * N_CLASSES + tid];
        out[tid] = acc;
    }
}

extern "C" void kernel_launch(void* const* d_in, const int* in_sizes, int n_in,
                              void* d_out, int out_size, void* d_ws, size_t ws_size,
                              hipStream_t stream) {
    const float* xp  = (const float*)d_in[0];
    const float* w1  = (const float*)d_in[2];
    const float* b1  = (const float*)d_in[3];
    const float* wv  = (const float*)d_in[10];
    const float* bv  = (const float*)d_in[11];
    const float* wa  = (const float*)d_in[12];
    const float* ba  = (const float*)d_in[13];
    const float* wb  = (const float*)d_in[14];
    const float* bb  = (const float*)d_in[15];
    const float* acw = (const float*)d_in[16];
    const float* acb = (const float*)d_in[17];
    const float* c1w = (const float*)d_in[18];
    const float* c1b = (const float*)d_in[19];
    const float* c2w = (const float*)d_in[20];
    const float* c2b = (const float*)d_in[21];
    float* out = (float*)d_out;

    char* ws = (char*)d_ws;
    __hip_bfloat16* w1t = (__hip_bfloat16*)(ws + WS_W1T);
    __hip_bfloat16* wvt = (__hip_bfloat16*)(ws + WS_WVT);
    __hip_bfloat16* wat = (__hip_bfloat16*)(ws + WS_WAT);
    __hip_bfloat16* wbt = (__hip_bfloat16*)(ws + WS_WBT);

    hipLaunchKernelGGL(convert_weights, dim3(112), dim3(256), 0, stream,
                       w1, wv, wa, wb, w1t, wvt, wat, wbt);

    if (ws_size >= WS_NEED2) {
        unsigned int* counter = (unsigned int*)(ws + WS_CNT);
        float* p1 = (float*)(ws + WS_P1);
        __hip_bfloat16* h  = (__hip_bfloat16*)(ws + WS_H);
        hipMemsetAsync(counter, 0, 4, stream);
        hipLaunchKernelGGL(mcat_stage1g, dim3(G1), dim3(256), 0, stream, xp, w1t, b1, h);
        hipLaunchKernelGGL(mcat_stage2, dim3(GB), dim3(512), 0, stream,
                           h, wvt, bv, wat, ba, wbt, bb, acw, acb, p1, counter,
                           c1w, c1b, c2w, c2b, out);
    } else {
        float* p1 = (float*)(ws + WS_P1F);
        float* p2 = (float*)(ws + WS_P2F);
        hipLaunchKernelGGL(mcat_mainF, dim3(NBLK), dim3(512), 0, stream,
                           xp, w1t, b1, wvt, bv, wat, ba, wbt, bb, acw, acb, p1);
        hipLaunchKernelGGL(mcat_fin_a, dim3(NB2), dim3(256), 0, stream, p1, p2);
        hipLaunchKernelGGL(mcat_fin_b, dim3(1), dim3(256), 0, stream,
                           p2, c1w, c1b, c2w, c2b, out);
    }
}

// Round 3
// 519.954 us; speedup vs baseline: 1.1871x; 1.1871x over previous
//
#include <hip/hip_runtime.h>
#include <hip/hip_bf16.h>
#include <math.h>

#define D_IN 1024
#define D_HID 256
#define D_CLS 128
#define N_CLASSES 4
#define N_INST 50000

#define NPAD 50176                   // 392*128
#define G1 (NPAD / 64)               // 784 stage1 blocks (64 rows each)
#define RG2 128
#define GB (NPAD / RG2)              // 392
#define PSTR 258
#define NEG_BIG (-1e30f)

// ---- fallback-path geometry (R3, proven) ----
#define ROWS 64
#define NBLK ((N_INST + ROWS - 1) / ROWS)   // 782
#define NB2 64
#define CHUNK ((NBLK + NB2 - 1) / NB2)      // 13

// ---- workspace layout (bytes) ----
#define WS_W1T   0u
#define WS_WVT   524288u
#define WS_WAT   655360u
#define WS_WBT   786432u
#define WS_CNT   917504u
#define WS_P1    917760u                               // 392*258*4 = 404544 -> ends 1322304
#define WS_H     1322304u                              // NPAD*256*2 = 25690112
#define WS_NEED2 ((size_t)WS_H + 25690112u)            // ~27 MB
// fallback offsets
#define WS_P1F   917504u
#define WS_P2F   1724800u

typedef __attribute__((ext_vector_type(8))) short bf16x8;
typedef __attribute__((ext_vector_type(4))) float f32x4;

__device__ __forceinline__ short f2bf(float x) {
    __hip_bfloat16 h = __float2bfloat16(x);
    return *reinterpret_cast<short*>(&h);
}
__device__ __forceinline__ float fast_tanh(float x) {
    float e = __expf(2.f * x);
    return 1.f - 2.f * __builtin_amdgcn_rcpf(e + 1.f);
}
__device__ __forceinline__ float fast_sigmoid(float x) {
    return __builtin_amdgcn_rcpf(1.f + __expf(-x));
}
__device__ __forceinline__ bf16x8 cvt8(float4 a, float4 b) {
    bf16x8 r;
    r[0] = f2bf(a.x); r[1] = f2bf(a.y); r[2] = f2bf(a.z); r[3] = f2bf(a.w);
    r[4] = f2bf(b.x); r[5] = f2bf(b.y); r[6] = f2bf(b.z); r[7] = f2bf(b.w);
    return r;
}
__device__ __forceinline__ bf16x8 cvt8v(f32x4 a, f32x4 b) {
    bf16x8 r;
    r[0] = f2bf(a[0]); r[1] = f2bf(a[1]); r[2] = f2bf(a[2]); r[3] = f2bf(a[3]);
    r[4] = f2bf(b[0]); r[5] = f2bf(b[1]); r[6] = f2bf(b[2]); r[7] = f2bf(b[3]);
    return r;
}
__device__ __forceinline__ bf16x8 load_cvt8(const float* __restrict__ p) {
    return cvt8(*(const float4*)p, *(const float4*)(p + 4));
}
// async global->LDS DMA, 16B per lane. LDS dest is wave-uniform base + lane*16.
__device__ __forceinline__ void async_ld16(const float* g, float* l) {
    __builtin_amdgcn_global_load_lds(
        (const __attribute__((address_space(1))) void*)g,
        (__attribute__((address_space(3))) void*)l, 16, 0, 0);
}

// ================= weight convert + transpose (fp32 [K][256] -> bf16 [256][K]) =================
__global__ void convert_weights(const float* __restrict__ w1, const float* __restrict__ wv,
                                const float* __restrict__ wa, const float* __restrict__ wb,
                                __hip_bfloat16* __restrict__ w1t, __hip_bfloat16* __restrict__ wvt,
                                __hip_bfloat16* __restrict__ wat, __hip_bfloat16* __restrict__ wbt) {
    __shared__ __hip_bfloat16 T[64][68];
    int b = blockIdx.x, tid = threadIdx.x;
    const float* src; __hip_bfloat16* dst; int K, tr, tc;
    if (b < 64) { src = w1; dst = w1t; K = D_IN; tr = b >> 2; tc = b & 3; }
    else {
        int m = (b - 64) >> 4, t = (b - 64) & 15;
        src = (m == 0) ? wv : (m == 1) ? wa : wb;
        dst = (m == 0) ? wvt : (m == 1) ? wat : wbt;
        K = D_HID; tr = t >> 2; tc = t & 3;
    }
    int k0 = tr * 64, n0 = tc * 64;
#pragma unroll
    for (int p = 0; p < 4; p++) {
        int lin = p * 256 + tid;
        int r = lin >> 4;
        int c4 = (lin & 15) << 2;
        float4 v = *(const float4*)(src + (size_t)(k0 + r) * D_HID + n0 + c4);
        T[c4 + 0][r] = __float2bfloat16(v.x);
        T[c4 + 1][r] = __float2bfloat16(v.y);
        T[c4 + 2][r] = __float2bfloat16(v.z);
        T[c4 + 3][r] = __float2bfloat16(v.w);
    }
    __syncthreads();
#pragma unroll
    for (int p = 0; p < 4; p++) {
        int lin = p * 256 + tid;
        int n = lin >> 4;
        int kq = (lin & 15) << 2;
        ushort4 o;
        o.x = *(unsigned short*)&T[n][kq + 0];
        o.y = *(unsigned short*)&T[n][kq + 1];
        o.z = *(unsigned short*)&T[n][kq + 2];
        o.w = *(unsigned short*)&T[n][kq + 3];
        *(ushort4*)(dst + (size_t)(n0 + n) * K + k0 + kq) = o;
    }
}

// ================= stage 1 (v3: global_load_lds DMA ring + counted vmcnt) =================
// h = relu(X @ W1 + b1). 64 rows x 256 cols per block, 4 waves. X staged ONCE per block
// into a 4-buffer LDS ring via async DMA (no VGPR round-trip, no vmcnt(0) drain at
// barriers -> 3 K-tiles of HBM loads stay in flight). Source-side XOR swizzle
// (granule (l&7)^(l>>3), 16B granules) with linear LDS dest; same XOR on ds_read ->
// 2-way bank access (free). W fragments prefetched 1 step ahead into registers
// (L2-resident). Raw s_barrier + hand-counted vmcnt per the 2-phase T3/T4 recipe.
// h written in the MFMA-tiled layout consumed by stage2 (identical to prior version).
__global__ __launch_bounds__(256, 3) void mcat_stage1h(const float* __restrict__ xp,
                                                       const __hip_bfloat16* __restrict__ w1t,
                                                       const float* __restrict__ b1,
                                                       __hip_bfloat16* __restrict__ hout) {
    __shared__ float Xs[4][2048];   // 4 ring buffers, each 64 rows x 32 fp32 (8KB)

    const int tid  = threadIdx.x;
    const int wave = tid >> 6;
    const int lane = tid & 63;
    const int quad = lane >> 4;
    const int l16  = lane & 15;
    const int row0 = blockIdx.x * 64;
    const int t128 = blockIdx.x >> 1;
    const int rhalf = blockIdx.x & 1;

    // per-lane DMA source pieces: each wave stages chunks {2w, 2w+1} (8 rows x 128B each)
    // lane l -> row chunk*8 + (l>>3), swizzled granule (l&7)^(l>>3) (granule = 4 floats)
    const int dma_rsub = lane >> 3;               // 0..7 (also the swizzle key for its row)
    const int dma_gran = (lane & 7) ^ dma_rsub;   // source granule index
    auto stage = [&](int buf, int kc) {
#pragma unroll
        for (int c = 0; c < 2; c++) {
            const int chunk = wave * 2 + c;
            int rg = row0 + chunk * 8 + dma_rsub;
            if (rg > N_INST - 1) rg = N_INST - 1;   // clamp: valid memory, masked in stage2
            async_ld16(xp + (size_t)rg * D_IN + kc + dma_gran * 4, &Xs[buf][chunk * 256]);
        }
    };

    // per-lane W row pointers (B-frag: col = wave*64 + ct*16 + l16, k-offset = quad*8)
    const __hip_bfloat16* wb[4];
#pragma unroll
    for (int ct = 0; ct < 4; ct++)
        wb[ct] = w1t + (size_t)(wave * 64 + ct * 16 + l16) * D_IN + quad * 8;

    f32x4 acc[4][4];
    f32x4 zero = {0.f, 0.f, 0.f, 0.f};
#pragma unroll
    for (int i = 0; i < 4; i++)
#pragma unroll
        for (int j = 0; j < 4; j++) acc[i][j] = zero;

    // prologue: stage buffers 0..2 (vmem order: X0, [W0], X1, X2 - any W placement is safe)
    stage(0, 0);
    bf16x8 wcur[4];
#pragma unroll
    for (int ct = 0; ct < 4; ct++) wcur[ct] = *(const bf16x8*)(wb[ct]);
    stage(1, 32);
    stage(2, 64);

    const int key = l16 & 7;   // read-side swizzle key (row & 7, rt*16 preserves low 3 bits)
#pragma unroll 1
    for (int t = 0; t < 32; t++) {
        // counted waits: steady-state vmcnt(2) completes X(t) (>=4 newer DMAs outstanding)
        // while X(t+1), X(t+2) stay in flight across the barrier.
        if (t == 0)      asm volatile("s_waitcnt vmcnt(4)" ::: "memory");
        else if (t < 29) asm volatile("s_waitcnt vmcnt(2)" ::: "memory");
        else             asm volatile("s_waitcnt vmcnt(0)" ::: "memory");
        __builtin_amdgcn_s_barrier();

        bf16x8 wnx[4];
        if (t < 31) {
#pragma unroll
            for (int ct = 0; ct < 4; ct++)
                wnx[ct] = *(const bf16x8*)(wb[ct] + (t + 1) * 32);
        }
        if (t < 29) stage((t + 3) & 3, (t + 3) * 32);

        const float* bufp = &Xs[t & 3][0];
#pragma unroll
        for (int rt = 0; rt < 4; rt++) {
            const float* rp = bufp + (rt * 16 + l16) * 32;
            f32x4 lo = *(const f32x4*)(rp + (((2 * quad) ^ key) << 2));
            f32x4 hi = *(const f32x4*)(rp + (((2 * quad + 1) ^ key) << 2));
            bf16x8 af = cvt8v(lo, hi);
#pragma unroll
            for (int ct = 0; ct < 4; ct++)
                acc[rt][ct] = __builtin_amdgcn_mfma_f32_16x16x32_bf16(af, wcur[ct], acc[rt][ct], 0, 0, 0);
        }
        if (t < 31) {
#pragma unroll
            for (int ct = 0; ct < 4; ct++) wcur[ct] = wnx[ct];
        }
    }

    // epilogue: bias+relu -> tiled h (identical layout to previous stage1)
#pragma unroll
    for (int ct = 0; ct < 4; ct++) {
        const int col = wave * 64 + ct * 16 + l16;
        const float bias = b1[col];
        __hip_bfloat16* hb = hout + (((size_t)(t128 * 8 + (col >> 5)) * 4 + ((col >> 3) & 3)) << 10)
                                  + rhalf * 512 + (col & 7);
#pragma unroll
        for (int rt = 0; rt < 4; rt++)
#pragma unroll
            for (int r = 0; r < 4; r++) {
                int row = rt * 16 + quad * 4 + r;
                hb[row * 8] = __float2bfloat16(fmaxf(acc[rt][ct][r] + bias, 0.f));
            }
    }
}

// ================= stage 2: v/a/b GEMMs + gated attention + partials + fused finalize =================
__global__ __launch_bounds__(512, 1) void mcat_stage2(const __hip_bfloat16* __restrict__ h,
                          const __hip_bfloat16* __restrict__ wvt, const float* __restrict__ bv,
                          const __hip_bfloat16* __restrict__ wat, const float* __restrict__ ba,
                          const __hip_bfloat16* __restrict__ wbt, const float* __restrict__ bb,
                          const float* __restrict__ acw, const float* __restrict__ acb,
                          float* __restrict__ p1, unsigned int* __restrict__ counter,
                          const float* __restrict__ c1w, const float* __restrict__ c1b,
                          const float* __restrict__ c2w, const float* __restrict__ c2b,
                          float* __restrict__ out) {
    __shared__ __hip_bfloat16 Vs[RG2][264];
    __shared__ float Apart[8][RG2];
    __shared__ float ExpW[RG2];
    __shared__ float smx[4];
    __shared__ float scb[GB];
    __shared__ float pooled[D_HID];
    __shared__ float r1v[D_CLS];

    const int tid  = threadIdx.x;
    const int wave = tid >> 6;
    const int lane = tid & 63;
    const int quad = lane >> 4;
    const int l16  = lane & 15;
    const int cb   = wave * 32;
    const int row0 = blockIdx.x * RG2;

    f32x4 acc[8][2];
    f32x4 zero = {0.f, 0.f, 0.f, 0.f};

    // ---- v = h @ Wv + bv : A direct from tiled h ----
    const __hip_bfloat16* hb = h + (size_t)blockIdx.x * 32768 + quad * 1024 + l16 * 8;
#pragma unroll
    for (int i = 0; i < 8; i++) { acc[i][0] = zero; acc[i][1] = zero; }
    {
        const __hip_bfloat16* w0 = wvt + (size_t)(cb + l16) * D_HID + quad * 8;
        const __hip_bfloat16* w1p = w0 + 16 * D_HID;
#pragma unroll
        for (int ks = 0; ks < 8; ks++) {
            bf16x8 b0 = *(const bf16x8*)(w0 + ks * 32);
            bf16x8 b1f = *(const bf16x8*)(w1p + ks * 32);
#pragma unroll
            for (int rt = 0; rt < 8; rt++) {
                bf16x8 af = *(const bf16x8*)(hb + ks * 4096 + rt * 128);
                acc[rt][0] = __builtin_amdgcn_mfma_f32_16x16x32_bf16(af, b0, acc[rt][0], 0, 0, 0);
                acc[rt][1] = __builtin_amdgcn_mfma_f32_16x16x32_bf16(af, b1f, acc[rt][1], 0, 0, 0);
            }
        }
    }
#pragma unroll
    for (int ct = 0; ct < 2; ct++) {
        int col = cb + ct * 16 + l16;
        float bias = bv[col];
#pragma unroll
        for (int rt = 0; rt < 8; rt++)
#pragma unroll
            for (int r = 0; r < 4; r++)
                Vs[rt * 16 + quad * 4 + r][col] = __float2bfloat16(acc[rt][ct][r] + bias);
    }
    __syncthreads();

    // ---- a = tanh(v @ Wa + ba), kept in regs ----
    float a_reg[8][2][4];
#pragma unroll
    for (int i = 0; i < 8; i++) { acc[i][0] = zero; acc[i][1] = zero; }
    {
        const __hip_bfloat16* w0 = wat + (size_t)(cb + l16) * D_HID + quad * 8;
        const __hip_bfloat16* w1p = w0 + 16 * D_HID;
#pragma unroll
        for (int ks = 0; ks < 8; ks++) {
            bf16x8 b0 = *(const bf16x8*)(w0 + ks * 32);
            bf16x8 b1f = *(const bf16x8*)(w1p + ks * 32);
#pragma unroll
            for (int rt = 0; rt < 8; rt++) {
                bf16x8 af = *(const bf16x8*)&Vs[rt * 16 + l16][ks * 32 + quad * 8];
                acc[rt][0] = __builtin_amdgcn_mfma_f32_16x16x32_bf16(af, b0, acc[rt][0], 0, 0, 0);
                acc[rt][1] = __builtin_amdgcn_mfma_f32_16x16x32_bf16(af, b1f, acc[rt][1], 0, 0, 0);
            }
        }
    }
#pragma unroll
    for (int ct = 0; ct < 2; ct++) {
        float bias = ba[cb + ct * 16 + l16];
#pragma unroll
        for (int rt = 0; rt < 8; rt++)
#pragma unroll
            for (int r = 0; r < 4; r++)
                a_reg[rt][ct][r] = fast_tanh(acc[rt][ct][r] + bias);
    }

    // ---- b-gate GEMM + fold attention dot ----
#pragma unroll
    for (int i = 0; i < 8; i++) { acc[i][0] = zero; acc[i][1] = zero; }
    {
        const __hip_bfloat16* w0 = wbt + (size_t)(cb + l16) * D_HID + quad * 8;
        const __hip_bfloat16* w1p = w0 + 16 * D_HID;
#pragma unroll
        for (int ks = 0; ks < 8; ks++) {
            bf16x8 b0 = *(const bf16x8*)(w0 + ks * 32);
            bf16x8 b1f = *(const bf16x8*)(w1p + ks * 32);
#pragma unroll
            for (int rt = 0; rt < 8; rt++) {
                bf16x8 af = *(const bf16x8*)&Vs[rt * 16 + l16][ks * 32 + quad * 8];
                acc[rt][0] = __builtin_amdgcn_mfma_f32_16x16x32_bf16(af, b0, acc[rt][0], 0, 0, 0);
                acc[rt][1] = __builtin_amdgcn_mfma_f32_16x16x32_bf16(af, b1f, acc[rt][1], 0, 0, 0);
            }
        }
    }
    {
        float acw0 = acw[cb + l16], acw1 = acw[cb + 16 + l16];
        float bb0 = bb[cb + l16],  bb1 = bb[cb + 16 + l16];
        float sp[8][4];
#pragma unroll
        for (int rt = 0; rt < 8; rt++)
#pragma unroll
            for (int r = 0; r < 4; r++) {
                float g0 = a_reg[rt][0][r] * fast_sigmoid(acc[rt][0][r] + bb0);
                float g1 = a_reg[rt][1][r] * fast_sigmoid(acc[rt][1][r] + bb1);
                sp[rt][r] = g0 * acw0 + g1 * acw1;
            }
#pragma unroll
        for (int off = 1; off < 16; off <<= 1)
#pragma unroll
            for (int rt = 0; rt < 8; rt++)
#pragma unroll
                for (int r = 0; r < 4; r++)
                    sp[rt][r] += __shfl_xor(sp[rt][r], off, 16);
        if (l16 == 0) {
#pragma unroll
            for (int rt = 0; rt < 8; rt++)
#pragma unroll
                for (int r = 0; r < 4; r++)
                    Apart[wave][rt * 16 + quad * 4 + r] = sp[rt][r];
        }
    }
    __syncthreads();

    // ---- block-local online softmax over 128 rows ----
    if (tid < 64) {
        float A0 = acb[0], A1 = acb[0];
#pragma unroll
        for (int w = 0; w < 8; w++) { A0 += Apart[w][tid]; A1 += Apart[w][tid + 64]; }
        bool v0 = (row0 + tid) < N_INST;
        bool v1 = (row0 + 64 + tid) < N_INST;
        if (!v0) A0 = NEG_BIG;
        if (!v1) A1 = NEG_BIG;
        float m = fmaxf(A0, A1);
#pragma unroll
        for (int off = 32; off > 0; off >>= 1) m = fmaxf(m, __shfl_xor(m, off));
        float e0 = v0 ? __expf(A0 - m) : 0.f;
        float e1 = v1 ? __expf(A1 - m) : 0.f;
        ExpW[tid] = e0; ExpW[tid + 64] = e1;
        float ssum = e0 + e1;
#pragma unroll
        for (int off = 32; off > 0; off >>= 1) ssum += __shfl_xor(ssum, off);
        if (tid == 0) {
            p1[(size_t)blockIdx.x * PSTR + 0] = m;
            p1[(size_t)blockIdx.x * PSTR + 1] = ssum;
        }
    }
    __syncthreads();
    if (tid < 256) {
        float p = 0.f;
#pragma unroll 8
        for (int n = 0; n < RG2; n++)
            p += ExpW[n] * __bfloat162float(Vs[n][tid]);
        p1[(size_t)blockIdx.x * PSTR + 2 + tid] = p;
    }

    // ---- last-block finalize (atomic ticket) ----
    __syncthreads();
    if (tid == 0) {
        __threadfence();
        unsigned int old = __hip_atomic_fetch_add(counter, 1u, __ATOMIC_ACQ_REL, __HIP_MEMORY_SCOPE_AGENT);
        smx[3] = (old == GB - 1) ? 1.f : 0.f;
    }
    __syncthreads();
    if (smx[3] == 0.f) return;
    __threadfence();

    {
        float mloc = NEG_BIG;
        for (int b = tid; b < GB; b += 512) mloc = fmaxf(mloc, p1[(size_t)b * PSTR]);
#pragma unroll
        for (int off = 32; off > 0; off >>= 1) mloc = fmaxf(mloc, __shfl_xor(mloc, off));
        if (lane == 0) ExpW[wave] = mloc;
    }
    __syncthreads();
    if (tid == 0) {
        float M = NEG_BIG;
#pragma unroll
        for (int w = 0; w < 8; w++) M = fmaxf(M, ExpW[w]);
        smx[0] = M;
    }
    __syncthreads();
    {
        float M = smx[0];
        float sl = 0.f;
        for (int b = tid; b < GB; b += 512) {
            float s = __expf(p1[(size_t)b * PSTR] - M);
            scb[b] = s;
            sl += s * p1[(size_t)b * PSTR + 1];
        }
#pragma unroll
        for (int off = 32; off > 0; off >>= 1) sl += __shfl_xor(sl, off);
        if (lane == 0) ExpW[8 + wave] = sl;
    }
    __syncthreads();
    if (tid == 0) {
        float S = 0.f;
#pragma unroll
        for (int w = 0; w < 8; w++) S += ExpW[8 + w];
        smx[1] = S;
    }
    __syncthreads();
    if (tid < 256) {
        float p = 0.f;
        for (int b = 0; b < GB; b++)
            p += scb[b] * p1[(size_t)b * PSTR + 2 + tid];
        pooled[tid] = p / smx[1];
    }
    __syncthreads();
    if (tid < D_CLS) {
        float a2 = c1b[tid];
#pragma unroll 8
        for (int d = 0; d < D_HID; d++)
            a2 += pooled[d] * c1w[(size_t)d * D_CLS + tid];
        r1v[tid] = fmaxf(a2, 0.f);
    }
    __syncthreads();
    if (tid < N_CLASSES) {
        float a2 = c2b[tid];
#pragma unroll 8
        for (int j = 0; j < D_CLS; j++)
            a2 += r1v[j] * c2w[(size_t)j * N_CLASSES + tid];
        out[tid] = a2;
    }
}

// ===================== fallback path (R3, proven) =====================
__device__ __forceinline__ void gemm256_w8(const __hip_bfloat16 (*S)[264],
                                           const __hip_bfloat16* __restrict__ Wt,
                                           int colbase, int quad, int l16, f32x4 acc[4][2]) {
    f32x4 zero = {0.f, 0.f, 0.f, 0.f};
#pragma unroll
    for (int i = 0; i < 4; i++) { acc[i][0] = zero; acc[i][1] = zero; }
    const __hip_bfloat16* w0 = Wt + (size_t)(colbase + l16) * D_HID + quad * 8;
    const __hip_bfloat16* w1 = w0 + 16 * D_HID;
#pragma unroll
    for (int ks = 0; ks < 8; ks++) {
        bf16x8 af[4];
#pragma unroll
        for (int rt = 0; rt < 4; rt++)
            af[rt] = *(const bf16x8*)&S[rt * 16 + l16][ks * 32 + quad * 8];
        bf16x8 b0 = *(const bf16x8*)(w0 + ks * 32);
        bf16x8 b1 = *(const bf16x8*)(w1 + ks * 32);
#pragma unroll
        for (int rt = 0; rt < 4; rt++) {
            acc[rt][0] = __builtin_amdgcn_mfma_f32_16x16x32_bf16(af[rt], b0, acc[rt][0], 0, 0, 0);
            acc[rt][1] = __builtin_amdgcn_mfma_f32_16x16x32_bf16(af[rt], b1, acc[rt][1], 0, 0, 0);
        }
    }
}

__global__ __launch_bounds__(512, 4) void mcat_mainF(const float* __restrict__ xsrc,
                          const __hip_bfloat16* __restrict__ w1t, const float* __restrict__ b1,
                          const __hip_bfloat16* __restrict__ wvt, const float* __restrict__ bv,
                          const __hip_bfloat16* __restrict__ wat, const float* __restrict__ ba,
                          const __hip_bfloat16* __restrict__ wbt, const float* __restrict__ bb,
                          const float* __restrict__ acw, const float* __restrict__ acb,
                          float* __restrict__ partials) {
    __shared__ __hip_bfloat16 Hs[ROWS][264];
    __shared__ __hip_bfloat16 Vs[ROWS][264];
    __shared__ float Apart[8][ROWS];
    __shared__ float ExpW[ROWS];
    const int tid  = threadIdx.x;
    const int wave = tid >> 6;
    const int lane = tid & 63;
    const int quad = lane >> 4;
    const int l16  = lane & 15;
    const int colbase = wave * 32;
    const int row0 = blockIdx.x * ROWS;
    f32x4 acc[4][2];
    f32x4 zero = {0.f, 0.f, 0.f, 0.f};
#pragma unroll
    for (int i = 0; i < 4; i++) { acc[i][0] = zero; acc[i][1] = zero; }
    const float* xf_base[4];
#pragma unroll
    for (int rt = 0; rt < 4; rt++) {
        int r = row0 + rt * 16 + l16;
        if (r > N_INST - 1) r = N_INST - 1;
        xf_base[rt] = xsrc + (size_t)r * D_IN + quad * 8;
    }
    const __hip_bfloat16* wb0 = w1t + (size_t)(colbase + l16) * D_IN + quad * 8;
    const __hip_bfloat16* wb1 = wb0 + 16 * D_IN;
    for (int kc = 0; kc < D_IN; kc += 32) {
        bf16x8 af[4];
#pragma unroll
        for (int rt = 0; rt < 4; rt++) af[rt] = load_cvt8(xf_base[rt] + kc);
        bf16x8 b0 = *(const bf16x8*)(wb0 + kc);
        bf16x8 b1 = *(const bf16x8*)(wb1 + kc);
#pragma unroll
        for (int rt = 0; rt < 4; rt++) {
            acc[rt][0] = __builtin_amdgcn_mfma_f32_16x16x32_bf16(af[rt], b0, acc[rt][0], 0, 0, 0);
            acc[rt][1] = __builtin_amdgcn_mfma_f32_16x16x32_bf16(af[rt], b1, acc[rt][1], 0, 0, 0);
        }
    }
#pragma unroll
    for (int ct = 0; ct < 2; ct++) {
        int col = colbase + ct * 16 + l16;
        float bias = b1[col];
#pragma unroll
        for (int rt = 0; rt < 4; rt++)
#pragma unroll
            for (int r = 0; r < 4; r++)
                Hs[rt * 16 + quad * 4 + r][col] = __float2bfloat16(fmaxf(acc[rt][ct][r] + bias, 0.f));
    }
    __syncthreads();
    gemm256_w8(Hs, wvt, colbase, quad, l16, acc);
#pragma unroll
    for (int ct = 0; ct < 2; ct++) {
        int col = colbase + ct * 16 + l16;
        float bias = bv[col];
#pragma unroll
        for (int rt = 0; rt < 4; rt++)
#pragma unroll
            for (int r = 0; r < 4; r++)
                Vs[rt * 16 + quad * 4 + r][col] = __float2bfloat16(acc[rt][ct][r] + bias);
    }
    __syncthreads();
    float a_reg[4][2][4];
    gemm256_w8(Vs, wat, colbase, quad, l16, acc);
#pragma unroll
    for (int ct = 0; ct < 2; ct++) {
        float bias = ba[colbase + ct * 16 + l16];
#pragma unroll
        for (int rt = 0; rt < 4; rt++)
#pragma unroll
            for (int r = 0; r < 4; r++)
                a_reg[rt][ct][r] = fast_tanh(acc[rt][ct][r] + bias);
    }
    gemm256_w8(Vs, wbt, colbase, quad, l16, acc);
    {
        float acw0 = acw[colbase + l16];
        float acw1 = acw[colbase + 16 + l16];
        float bias0 = bb[colbase + l16];
        float bias1 = bb[colbase + 16 + l16];
        float sp[4][4];
#pragma unroll
        for (int rt = 0; rt < 4; rt++)
#pragma unroll
            for (int r = 0; r < 4; r++) {
                float g0 = a_reg[rt][0][r] * fast_sigmoid(acc[rt][0][r] + bias0);
                float g1 = a_reg[rt][1][r] * fast_sigmoid(acc[rt][1][r] + bias1);
                sp[rt][r] = g0 * acw0 + g1 * acw1;
            }
#pragma unroll
        for (int off = 1; off < 16; off <<= 1)
#pragma unroll
            for (int rt = 0; rt < 4; rt++)
#pragma unroll
                for (int r = 0; r < 4; r++)
                    sp[rt][r] += __shfl_xor(sp[rt][r], off, 16);
        if (l16 == 0) {
#pragma unroll
            for (int rt = 0; rt < 4; rt++)
#pragma unroll
                for (int r = 0; r < 4; r++)
                    Apart[wave][rt * 16 + quad * 4 + r] = sp[rt][r];
        }
    }
    __syncthreads();
    if (tid < 64) {
        bool valid = (row0 + tid) < N_INST;
        float A = acb[0];
#pragma unroll
        for (int w = 0; w < 8; w++) A += Apart[w][tid];
        if (!valid) A = NEG_BIG;
        float m = A;
#pragma unroll
        for (int off = 32; off > 0; off >>= 1) m = fmaxf(m, __shfl_xor(m, off));
        float e = valid ? __expf(A - m) : 0.f;
        ExpW[tid] = e;
        float ssum = e;
#pragma unroll
        for (int off = 32; off > 0; off >>= 1) ssum += __shfl_xor(ssum, off);
        if (tid == 0) {
            partials[(size_t)blockIdx.x * PSTR + 0] = m;
            partials[(size_t)blockIdx.x * PSTR + 1] = ssum;
        }
    }
    __syncthreads();
    if (tid < 256) {
        float p = 0.f;
#pragma unroll 8
        for (int n = 0; n < 64; n++)
            p += ExpW[n] * __bfloat162float(Vs[n][tid]);
        partials[(size_t)blockIdx.x * PSTR + 2 + tid] = p;
    }
}

__global__ void mcat_fin_a(const float* __restrict__ p1, float* __restrict__ p2) {
    __shared__ float sm[1];
    int g = blockIdx.x, tid = threadIdx.x;
    int lo = g * CHUNK;
    int hi = lo + CHUNK; if (hi > NBLK) hi = NBLK;
    if (tid < 64) {
        float m = NEG_BIG;
        if (lo + tid < hi) m = p1[(size_t)(lo + tid) * PSTR];
#pragma unroll
        for (int off = 32; off > 0; off >>= 1) m = fmaxf(m, __shfl_xor(m, off));
        if (tid == 0) sm[0] = m;
    }
    __syncthreads();
    float M = sm[0];
    float p = 0.f, sacc = 0.f;
    for (int b = lo; b < hi; b++) {
        float sc = __expf(p1[(size_t)b * PSTR] - M);
        sacc += sc * p1[(size_t)b * PSTR + 1];
        p += sc * p1[(size_t)b * PSTR + 2 + tid];
    }
    if (tid == 0) {
        p2[(size_t)g * PSTR + 0] = M;
        p2[(size_t)g * PSTR + 1] = sacc;
    }
    p2[(size_t)g * PSTR + 2 + tid] = p;
}

__global__ void mcat_fin_b(const float* __restrict__ p2,
                           const float* __restrict__ c1w, const float* __restrict__ c1b,
                           const float* __restrict__ c2w, const float* __restrict__ c2b,
                           float* __restrict__ out) {
    __shared__ float sm[2];
    __shared__ float sc[NB2];
    __shared__ float pooled[D_HID];
    __shared__ float r1[D_CLS];
    int tid = threadIdx.x;
    if (tid < 64) {
        float m = p2[(size_t)tid * PSTR];
#pragma unroll
        for (int off = 32; off > 0; off >>= 1) m = fmaxf(m, __shfl_xor(m, off));
        if (tid == 0) sm[0] = m;
    }
    __syncthreads();
    float M = sm[0];
    if (tid < 64) {
        float s = __expf(p2[(size_t)tid * PSTR] - M);
        sc[tid] = s;
        float Ssum = s * p2[(size_t)tid * PSTR + 1];
#pragma unroll
        for (int off = 32; off > 0; off >>= 1) Ssum += __shfl_xor(Ssum, off);
        if (tid == 0) sm[1] = Ssum;
    }
    __syncthreads();
    float S = sm[1];
    float p = 0.f;
#pragma unroll 8
    for (int b = 0; b < NB2; b++)
        p += sc[b] * p2[(size_t)b * PSTR + 2 + tid];
    pooled[tid] = p / S;
    __syncthreads();
    if (tid < D_CLS) {
        float acc = c1b[tid];
#pragma unroll 8
        for (int d = 0; d < D_HID; d++)
            acc += pooled[d] * c1w[(size_t)d * D_CLS + tid];
        r1[tid] = fmaxf(acc, 0.f);
    }
    __syncthreads();
    if (tid < N_CLASSES) {
        float acc = c2b[tid];
#pragma unroll 8
        for (int j = 0; j < D_CLS; j++)
            acc += r1[j] * c2w[(size_t)j * N_CLASSES + tid];
        out[tid] = acc;
    }
}

extern "C" void kernel_launch(void* const* d_in, const int* in_sizes, int n_in,
                              void* d_out, int out_size, void* d_ws, size_t ws_size,
                              hipStream_t stream) {
    const float* xp  = (const float*)d_in[0];
    const float* w1  = (const float*)d_in[2];
    const float* b1  = (const float*)d_in[3];
    const float* wv  = (const float*)d_in[10];
    const float* bv  = (const float*)d_in[11];
    const float* wa  = (const float*)d_in[12];
    const float* ba  = (const float*)d_in[13];
    const float* wb  = (const float*)d_in[14];
    const float* bb  = (const float*)d_in[15];
    const float* acw = (const float*)d_in[16];
    const float* acb = (const float*)d_in[17];
    const float* c1w = (const float*)d_in[18];
    const float* c1b = (const float*)d_in[19];
    const float* c2w = (const float*)d_in[20];
    const float* c2b = (const float*)d_in[21];
    float* out = (float*)d_out;

    char* ws = (char*)d_ws;
    __hip_bfloat16* w1t = (__hip_bfloat16*)(ws + WS_W1T);
    __hip_bfloat16* wvt = (__hip_bfloat16*)(ws + WS_WVT);
    __hip_bfloat16* wat = (__hip_bfloat16*)(ws + WS_WAT);
    __hip_bfloat16* wbt = (__hip_bfloat16*)(ws + WS_WBT);

    hipLaunchKernelGGL(convert_weights, dim3(112), dim3(256), 0, stream,
                       w1, wv, wa, wb, w1t, wvt, wat, wbt);

    if (ws_size >= WS_NEED2) {
        unsigned int* counter = (unsigned int*)(ws + WS_CNT);
        float* p1 = (float*)(ws + WS_P1);
        __hip_bfloat16* h  = (__hip_bfloat16*)(ws + WS_H);
        hipMemsetAsync(counter, 0, 4, stream);
        hipLaunchKernelGGL(mcat_stage1h, dim3(G1), dim3(256), 0, stream, xp, w1t, b1, h);
        hipLaunchKernelGGL(mcat_stage2, dim3(GB), dim3(512), 0, stream,
                           h, wvt, bv, wat, ba, wbt, bb, acw, acb, p1, counter,
                           c1w, c1b, c2w, c2b, out);
    } else {
        float* p1 = (float*)(ws + WS_P1F);
        float* p2 = (float*)(ws + WS_P2F);
        hipLaunchKernelGGL(mcat_mainF, dim3(NBLK), dim3(512), 0, stream,
                           xp, w1t, b1, wvt, bv, wat, ba, wbt, bb, acw, acb, p1);
        hipLaunchKernelGGL(mcat_fin_a, dim3(NB2), dim3(256), 0, stream, p1, p2);
        hipLaunchKernelGGL(mcat_fin_b, dim3(1), dim3(256), 0, stream,
                           p2, c1w, c1b, c2w, c2b, out);
    }
}

// Round 4
// 509.701 us; speedup vs baseline: 1.2110x; 1.0201x over previous
//
#include <hip/hip_runtime.h>
#include <hip/hip_bf16.h>
#include <math.h>

#define D_IN 1024
#define D_HID 256
#define D_CLS 128
#define N_CLASSES 4
#define N_INST 50000

#define NPAD 50176                   // 392*128
#define G1I (NPAD / 32)              // 1568 stage1 blocks (32 rows each)
#define RG2 128
#define GB (NPAD / RG2)              // 392
#define PSTR 258
#define NEG_BIG (-1e30f)

// ---- fallback-path geometry (R3, proven) ----
#define ROWS 64
#define NBLK ((N_INST + ROWS - 1) / ROWS)   // 782
#define NB2 64
#define CHUNK ((NBLK + NB2 - 1) / NB2)      // 13

// ---- workspace layout (bytes) ----
#define WS_W1T   0u
#define WS_WVT   524288u
#define WS_WAT   655360u
#define WS_WBT   786432u
#define WS_CNT   917504u
#define WS_P1    917760u                               // 392*258*4 = 404544 -> ends 1322304
#define WS_H     1322304u                              // NPAD*256*2 = 25690112
#define WS_NEED2 ((size_t)WS_H + 25690112u)            // ~27 MB
// fallback offsets
#define WS_P1F   917504u
#define WS_P2F   1724800u

typedef __attribute__((ext_vector_type(8))) short bf16x8;
typedef __attribute__((ext_vector_type(4))) float f32x4;

__device__ __forceinline__ short f2bf(float x) {
    __hip_bfloat16 h = __float2bfloat16(x);
    return *reinterpret_cast<short*>(&h);
}
__device__ __forceinline__ float fast_tanh(float x) {
    float e = __expf(2.f * x);
    return 1.f - 2.f * __builtin_amdgcn_rcpf(e + 1.f);
}
__device__ __forceinline__ float fast_sigmoid(float x) {
    return __builtin_amdgcn_rcpf(1.f + __expf(-x));
}
__device__ __forceinline__ bf16x8 cvt8(float4 a, float4 b) {
    bf16x8 r;
    r[0] = f2bf(a.x); r[1] = f2bf(a.y); r[2] = f2bf(a.z); r[3] = f2bf(a.w);
    r[4] = f2bf(b.x); r[5] = f2bf(b.y); r[6] = f2bf(b.z); r[7] = f2bf(b.w);
    return r;
}
__device__ __forceinline__ bf16x8 cvt8v(f32x4 a, f32x4 b) {
    bf16x8 r;
    r[0] = f2bf(a[0]); r[1] = f2bf(a[1]); r[2] = f2bf(a[2]); r[3] = f2bf(a[3]);
    r[4] = f2bf(b[0]); r[5] = f2bf(b[1]); r[6] = f2bf(b[2]); r[7] = f2bf(b[3]);
    return r;
}
__device__ __forceinline__ bf16x8 load_cvt8(const float* __restrict__ p) {
    return cvt8(*(const float4*)p, *(const float4*)(p + 4));
}
// async global->LDS DMA, 16B per lane. LDS dest is wave-uniform base + lane*16.
__device__ __forceinline__ void async_ld16(const float* g, float* l) {
    __builtin_amdgcn_global_load_lds(
        (const __attribute__((address_space(1))) void*)g,
        (__attribute__((address_space(3))) void*)l, 16, 0, 0);
}

// ================= weight convert =================
// frag==0: fp32 [K][256] -> bf16 [256][K] transpose (classic, used by fallback).
// frag==1: w1 additionally goes to FRAGMENT-LINEAR layout for stage1i:
//   tile t = kc*16 + wave*4 + ct  (kc 0..31, wave 0..3, ct 0..3)
//   w1f[t*512 + lane*8 + j] = w1[kc*32 + (lane>>4)*8 + j][wave*64 + ct*16 + (lane&15)]
//   -> each stage1 W load is ONE contiguous 1KB segment (vs 16x64B strided).
__global__ void convert_weights(const float* __restrict__ w1, const float* __restrict__ wv,
                                const float* __restrict__ wa, const float* __restrict__ wb,
                                __hip_bfloat16* __restrict__ w1t, __hip_bfloat16* __restrict__ wvt,
                                __hip_bfloat16* __restrict__ wat, __hip_bfloat16* __restrict__ wbt,
                                int frag) {
    __shared__ __hip_bfloat16 T[64][68];
    int b = blockIdx.x, tid = threadIdx.x;
    if (frag && b < 64) {
        // fragment-linear w1 pack: 512 tiles of 1KB; block handles 8 tiles
        const int group = tid >> 6, lane = tid & 63;
        const int colb = lane & 15;
        const int kb = (lane >> 4) * 8;
#pragma unroll
        for (int p = 0; p < 2; p++) {
            int tile = b * 8 + group * 2 + p;
            int kc = tile >> 4, w = (tile >> 2) & 3, ct = tile & 3;
            int col = w * 64 + ct * 16 + colb;
            const float* s = w1 + (size_t)(kc * 32 + kb) * D_HID + col;
            bf16x8 o;
#pragma unroll
            for (int j = 0; j < 8; j++) o[j] = f2bf(s[(size_t)j * D_HID]);
            *(bf16x8*)(w1t + (size_t)tile * 512 + lane * 8) = o;
        }
        return;
    }
    const float* src; __hip_bfloat16* dst; int K, tr, tc;
    if (b < 64) { src = w1; dst = w1t; K = D_IN; tr = b >> 2; tc = b & 3; }
    else {
        int m = (b - 64) >> 4, t = (b - 64) & 15;
        src = (m == 0) ? wv : (m == 1) ? wa : wb;
        dst = (m == 0) ? wvt : (m == 1) ? wat : wbt;
        K = D_HID; tr = t >> 2; tc = t & 3;
    }
    int k0 = tr * 64, n0 = tc * 64;
#pragma unroll
    for (int p = 0; p < 4; p++) {
        int lin = p * 256 + tid;
        int r = lin >> 4;
        int c4 = (lin & 15) << 2;
        float4 v = *(const float4*)(src + (size_t)(k0 + r) * D_HID + n0 + c4);
        T[c4 + 0][r] = __float2bfloat16(v.x);
        T[c4 + 1][r] = __float2bfloat16(v.y);
        T[c4 + 2][r] = __float2bfloat16(v.z);
        T[c4 + 3][r] = __float2bfloat16(v.w);
    }
    __syncthreads();
#pragma unroll
    for (int p = 0; p < 4; p++) {
        int lin = p * 256 + tid;
        int n = lin >> 4;
        int kq = (lin & 15) << 2;
        ushort4 o;
        o.x = *(unsigned short*)&T[n][kq + 0];
        o.y = *(unsigned short*)&T[n][kq + 1];
        o.z = *(unsigned short*)&T[n][kq + 2];
        o.w = *(unsigned short*)&T[n][kq + 3];
        *(ushort4*)(dst + (size_t)(n0 + n) * K + k0 + kq) = o;
    }
}

// ================= stage 1 (v4: 32-row blocks + fragment-linear W + DMA ring) =================
// h = relu(X @ W1 + b1). 32 rows x 256 cols per block, 4 waves (each 32 rows x 64 cols).
// Changes vs v3: (a) W loads are single-segment 1KB (fragment-linear w1f) -- kills the
// 16-segment/instr TA request storm that capped all prior variants at ~1 TB/s;
// (b) 1568 blocks -> ~6 blocks/CU available, launch_bounds(256,5) -> ~60% occupancy
// (grid previously capped occupancy at 38%). DMA ring schedule identical to v3 (scaled):
// 4-buffer ring, 1 DMA/wave/buffer, counted vmcnt 2/1/0, source-side XOR swizzle.
// h written in the MFMA-tiled layout consumed by stage2 (unchanged).
__global__ __launch_bounds__(256, 5) void mcat_stage1i(const float* __restrict__ xp,
                                                       const __hip_bfloat16* __restrict__ w1f,
                                                       const float* __restrict__ b1,
                                                       __hip_bfloat16* __restrict__ hout) {
    __shared__ float Xs[4][1024];   // 4 ring buffers, each 32 rows x 32 fp32 (4KB)

    const int tid  = threadIdx.x;
    const int wave = tid >> 6;
    const int lane = tid & 63;
    const int quad = lane >> 4;
    const int l16  = lane & 15;
    const int row0 = blockIdx.x * 32;
    const int t128 = blockIdx.x >> 2;
    const int qtr  = blockIdx.x & 3;

    // DMA: each wave stages its 8-row chunk (1KB) per buffer.
    // lane l -> row wave*8 + (l>>3), swizzled source granule (l&7)^(l>>3) (granule=16B)
    const int rsub = lane >> 3;
    const int gran = (lane & 7) ^ rsub;
    const float* xsrc;
    {
        int rg = row0 + wave * 8 + rsub;
        if (rg > N_INST - 1) rg = N_INST - 1;   // clamp: valid memory, masked in stage2
        xsrc = xp + (size_t)rg * D_IN + gran * 4;
    }

    // fragment-linear W base: tile (kc*16 + wave*4 + ct), lane-contiguous 16B
    const __hip_bfloat16* wbase = w1f + (size_t)wave * 4 * 512 + lane * 8;

    f32x4 acc[2][4];
    f32x4 zero = {0.f, 0.f, 0.f, 0.f};
#pragma unroll
    for (int i = 0; i < 2; i++)
#pragma unroll
        for (int j = 0; j < 4; j++) acc[i][j] = zero;

    // prologue: stage buffers 0..2; W0 fragments after stage(0) (vmcnt ordering)
    async_ld16(xsrc + 0, &Xs[0][wave * 256]);
    bf16x8 wcur[4];
#pragma unroll
    for (int ct = 0; ct < 4; ct++) wcur[ct] = *(const bf16x8*)(wbase + (size_t)ct * 512);
    async_ld16(xsrc + 32, &Xs[1][wave * 256]);
    async_ld16(xsrc + 64, &Xs[2][wave * 256]);

    const int key = l16 & 7;   // read-side swizzle key (row&7 == l16&7 since rt*16 preserves low 3 bits)
#pragma unroll 1
    for (int t = 0; t < 32; t++) {
        // counted waits: steady-state vmcnt(1) completes X(t)+X(t+1)+W(t) while X(t+2)
        // stays in flight across the barrier.
        if (t == 0)      asm volatile("s_waitcnt vmcnt(2)" ::: "memory");
        else if (t < 29) asm volatile("s_waitcnt vmcnt(1)" ::: "memory");
        else             asm volatile("s_waitcnt vmcnt(0)" ::: "memory");
        __builtin_amdgcn_s_barrier();

        bf16x8 wnx[4];
        if (t < 31) {
#pragma unroll
            for (int ct = 0; ct < 4; ct++)
                wnx[ct] = *(const bf16x8*)(wbase + (size_t)((t + 1) * 16 + ct) * 512);
        }
        if (t < 29) async_ld16(xsrc + (t + 3) * 32, &Xs[(t + 3) & 3][wave * 256]);

        const float* bufp = &Xs[t & 3][0];
#pragma unroll
        for (int rt = 0; rt < 2; rt++) {
            const float* rp = bufp + (rt * 16 + l16) * 32;
            f32x4 lo = *(const f32x4*)(rp + (((2 * quad) ^ key) << 2));
            f32x4 hi = *(const f32x4*)(rp + (((2 * quad + 1) ^ key) << 2));
            bf16x8 af = cvt8v(lo, hi);
#pragma unroll
            for (int ct = 0; ct < 4; ct++)
                acc[rt][ct] = __builtin_amdgcn_mfma_f32_16x16x32_bf16(af, wcur[ct], acc[rt][ct], 0, 0, 0);
        }
        if (t < 31) {
#pragma unroll
            for (int ct = 0; ct < 4; ct++) wcur[ct] = wnx[ct];
        }
    }

    // epilogue: bias+relu -> tiled h (row128 = qtr*32 + local row)
#pragma unroll
    for (int ct = 0; ct < 4; ct++) {
        const int col = wave * 64 + ct * 16 + l16;
        const float bias = b1[col];
        __hip_bfloat16* hb = hout + (((size_t)(t128 * 8 + (col >> 5)) * 4 + ((col >> 3) & 3)) << 10)
                                  + qtr * 256 + (col & 7);
#pragma unroll
        for (int rt = 0; rt < 2; rt++)
#pragma unroll
            for (int r = 0; r < 4; r++) {
                int row = rt * 16 + quad * 4 + r;
                hb[row * 8] = __float2bfloat16(fmaxf(acc[rt][ct][r] + bias, 0.f));
            }
    }
}

// ================= stage 2: v/a/b GEMMs + gated attention + partials + fused finalize =================
__global__ __launch_bounds__(512, 1) void mcat_stage2(const __hip_bfloat16* __restrict__ h,
                          const __hip_bfloat16* __restrict__ wvt, const float* __restrict__ bv,
                          const __hip_bfloat16* __restrict__ wat, const float* __restrict__ ba,
                          const __hip_bfloat16* __restrict__ wbt, const float* __restrict__ bb,
                          const float* __restrict__ acw, const float* __restrict__ acb,
                          float* __restrict__ p1, unsigned int* __restrict__ counter,
                          const float* __restrict__ c1w, const float* __restrict__ c1b,
                          const float* __restrict__ c2w, const float* __restrict__ c2b,
                          float* __restrict__ out) {
    __shared__ __hip_bfloat16 Vs[RG2][264];
    __shared__ float Apart[8][RG2];
    __shared__ float ExpW[RG2];
    __shared__ float smx[4];
    __shared__ float scb[GB];
    __shared__ float pooled[D_HID];
    __shared__ float r1v[D_CLS];

    const int tid  = threadIdx.x;
    const int wave = tid >> 6;
    const int lane = tid & 63;
    const int quad = lane >> 4;
    const int l16  = lane & 15;
    const int cb   = wave * 32;
    const int row0 = blockIdx.x * RG2;

    f32x4 acc[8][2];
    f32x4 zero = {0.f, 0.f, 0.f, 0.f};

    // ---- v = h @ Wv + bv : A direct from tiled h ----
    const __hip_bfloat16* hb = h + (size_t)blockIdx.x * 32768 + quad * 1024 + l16 * 8;
#pragma unroll
    for (int i = 0; i < 8; i++) { acc[i][0] = zero; acc[i][1] = zero; }
    {
        const __hip_bfloat16* w0 = wvt + (size_t)(cb + l16) * D_HID + quad * 8;
        const __hip_bfloat16* w1p = w0 + 16 * D_HID;
#pragma unroll
        for (int ks = 0; ks < 8; ks++) {
            bf16x8 b0 = *(const bf16x8*)(w0 + ks * 32);
            bf16x8 b1f = *(const bf16x8*)(w1p + ks * 32);
#pragma unroll
            for (int rt = 0; rt < 8; rt++) {
                bf16x8 af = *(const bf16x8*)(hb + ks * 4096 + rt * 128);
                acc[rt][0] = __builtin_amdgcn_mfma_f32_16x16x32_bf16(af, b0, acc[rt][0], 0, 0, 0);
                acc[rt][1] = __builtin_amdgcn_mfma_f32_16x16x32_bf16(af, b1f, acc[rt][1], 0, 0, 0);
            }
        }
    }
#pragma unroll
    for (int ct = 0; ct < 2; ct++) {
        int col = cb + ct * 16 + l16;
        float bias = bv[col];
#pragma unroll
        for (int rt = 0; rt < 8; rt++)
#pragma unroll
            for (int r = 0; r < 4; r++)
                Vs[rt * 16 + quad * 4 + r][col] = __float2bfloat16(acc[rt][ct][r] + bias);
    }
    __syncthreads();

    // ---- a = tanh(v @ Wa + ba), kept in regs ----
    float a_reg[8][2][4];
#pragma unroll
    for (int i = 0; i < 8; i++) { acc[i][0] = zero; acc[i][1] = zero; }
    {
        const __hip_bfloat16* w0 = wat + (size_t)(cb + l16) * D_HID + quad * 8;
        const __hip_bfloat16* w1p = w0 + 16 * D_HID;
#pragma unroll
        for (int ks = 0; ks < 8; ks++) {
            bf16x8 b0 = *(const bf16x8*)(w0 + ks * 32);
            bf16x8 b1f = *(const bf16x8*)(w1p + ks * 32);
#pragma unroll
            for (int rt = 0; rt < 8; rt++) {
                bf16x8 af = *(const bf16x8*)&Vs[rt * 16 + l16][ks * 32 + quad * 8];
                acc[rt][0] = __builtin_amdgcn_mfma_f32_16x16x32_bf16(af, b0, acc[rt][0], 0, 0, 0);
                acc[rt][1] = __builtin_amdgcn_mfma_f32_16x16x32_bf16(af, b1f, acc[rt][1], 0, 0, 0);
            }
        }
    }
#pragma unroll
    for (int ct = 0; ct < 2; ct++) {
        float bias = ba[cb + ct * 16 + l16];
#pragma unroll
        for (int rt = 0; rt < 8; rt++)
#pragma unroll
            for (int r = 0; r < 4; r++)
                a_reg[rt][ct][r] = fast_tanh(acc[rt][ct][r] + bias);
    }

    // ---- b-gate GEMM + fold attention dot ----
#pragma unroll
    for (int i = 0; i < 8; i++) { acc[i][0] = zero; acc[i][1] = zero; }
    {
        const __hip_bfloat16* w0 = wbt + (size_t)(cb + l16) * D_HID + quad * 8;
        const __hip_bfloat16* w1p = w0 + 16 * D_HID;
#pragma unroll
        for (int ks = 0; ks < 8; ks++) {
            bf16x8 b0 = *(const bf16x8*)(w0 + ks * 32);
            bf16x8 b1f = *(const bf16x8*)(w1p + ks * 32);
#pragma unroll
            for (int rt = 0; rt < 8; rt++) {
                bf16x8 af = *(const bf16x8*)&Vs[rt * 16 + l16][ks * 32 + quad * 8];
                acc[rt][0] = __builtin_amdgcn_mfma_f32_16x16x32_bf16(af, b0, acc[rt][0], 0, 0, 0);
                acc[rt][1] = __builtin_amdgcn_mfma_f32_16x16x32_bf16(af, b1f, acc[rt][1], 0, 0, 0);
            }
        }
    }
    {
        float acw0 = acw[cb + l16], acw1 = acw[cb + 16 + l16];
        float bb0 = bb[cb + l16],  bb1 = bb[cb + 16 + l16];
        float sp[8][4];
#pragma unroll
        for (int rt = 0; rt < 8; rt++)
#pragma unroll
            for (int r = 0; r < 4; r++) {
                float g0 = a_reg[rt][0][r] * fast_sigmoid(acc[rt][0][r] + bb0);
                float g1 = a_reg[rt][1][r] * fast_sigmoid(acc[rt][1][r] + bb1);
                sp[rt][r] = g0 * acw0 + g1 * acw1;
            }
#pragma unroll
        for (int off = 1; off < 16; off <<= 1)
#pragma unroll
            for (int rt = 0; rt < 8; rt++)
#pragma unroll
                for (int r = 0; r < 4; r++)
                    sp[rt][r] += __shfl_xor(sp[rt][r], off, 16);
        if (l16 == 0) {
#pragma unroll
            for (int rt = 0; rt < 8; rt++)
#pragma unroll
                for (int r = 0; r < 4; r++)
                    Apart[wave][rt * 16 + quad * 4 + r] = sp[rt][r];
        }
    }
    __syncthreads();

    // ---- block-local online softmax over 128 rows ----
    if (tid < 64) {
        float A0 = acb[0], A1 = acb[0];
#pragma unroll
        for (int w = 0; w < 8; w++) { A0 += Apart[w][tid]; A1 += Apart[w][tid + 64]; }
        bool v0 = (row0 + tid) < N_INST;
        bool v1 = (row0 + 64 + tid) < N_INST;
        if (!v0) A0 = NEG_BIG;
        if (!v1) A1 = NEG_BIG;
        float m = fmaxf(A0, A1);
#pragma unroll
        for (int off = 32; off > 0; off >>= 1) m = fmaxf(m, __shfl_xor(m, off));
        float e0 = v0 ? __expf(A0 - m) : 0.f;
        float e1 = v1 ? __expf(A1 - m) : 0.f;
        ExpW[tid] = e0; ExpW[tid + 64] = e1;
        float ssum = e0 + e1;
#pragma unroll
        for (int off = 32; off > 0; off >>= 1) ssum += __shfl_xor(ssum, off);
        if (tid == 0) {
            p1[(size_t)blockIdx.x * PSTR + 0] = m;
            p1[(size_t)blockIdx.x * PSTR + 1] = ssum;
        }
    }
    __syncthreads();
    if (tid < 256) {
        float p = 0.f;
#pragma unroll 8
        for (int n = 0; n < RG2; n++)
            p += ExpW[n] * __bfloat162float(Vs[n][tid]);
        p1[(size_t)blockIdx.x * PSTR + 2 + tid] = p;
    }

    // ---- last-block finalize (atomic ticket) ----
    __syncthreads();
    if (tid == 0) {
        __threadfence();
        unsigned int old = __hip_atomic_fetch_add(counter, 1u, __ATOMIC_ACQ_REL, __HIP_MEMORY_SCOPE_AGENT);
        smx[3] = (old == GB - 1) ? 1.f : 0.f;
    }
    __syncthreads();
    if (smx[3] == 0.f) return;
    __threadfence();

    {
        float mloc = NEG_BIG;
        for (int b = tid; b < GB; b += 512) mloc = fmaxf(mloc, p1[(size_t)b * PSTR]);
#pragma unroll
        for (int off = 32; off > 0; off >>= 1) mloc = fmaxf(mloc, __shfl_xor(mloc, off));
        if (lane == 0) ExpW[wave] = mloc;
    }
    __syncthreads();
    if (tid == 0) {
        float M = NEG_BIG;
#pragma unroll
        for (int w = 0; w < 8; w++) M = fmaxf(M, ExpW[w]);
        smx[0] = M;
    }
    __syncthreads();
    {
        float M = smx[0];
        float sl = 0.f;
        for (int b = tid; b < GB; b += 512) {
            float s = __expf(p1[(size_t)b * PSTR] - M);
            scb[b] = s;
            sl += s * p1[(size_t)b * PSTR + 1];
        }
#pragma unroll
        for (int off = 32; off > 0; off >>= 1) sl += __shfl_xor(sl, off);
        if (lane == 0) ExpW[8 + wave] = sl;
    }
    __syncthreads();
    if (tid == 0) {
        float S = 0.f;
#pragma unroll
        for (int w = 0; w < 8; w++) S += ExpW[8 + w];
        smx[1] = S;
    }
    __syncthreads();
    if (tid < 256) {
        float p = 0.f;
        for (int b = 0; b < GB; b++)
            p += scb[b] * p1[(size_t)b * PSTR + 2 + tid];
        pooled[tid] = p / smx[1];
    }
    __syncthreads();
    if (tid < D_CLS) {
        float a2 = c1b[tid];
#pragma unroll 8
        for (int d = 0; d < D_HID; d++)
            a2 += pooled[d] * c1w[(size_t)d * D_CLS + tid];
        r1v[tid] = fmaxf(a2, 0.f);
    }
    __syncthreads();
    if (tid < N_CLASSES) {
        float a2 = c2b[tid];
#pragma unroll 8
        for (int j = 0; j < D_CLS; j++)
            a2 += r1v[j] * c2w[(size_t)j * N_CLASSES + tid];
        out[tid] = a2;
    }
}

// ===================== fallback path (R3, proven) =====================
__device__ __forceinline__ void gemm256_w8(const __hip_bfloat16 (*S)[264],
                                           const __hip_bfloat16* __restrict__ Wt,
                                           int colbase, int quad, int l16, f32x4 acc[4][2]) {
    f32x4 zero = {0.f, 0.f, 0.f, 0.f};
#pragma unroll
    for (int i = 0; i < 4; i++) { acc[i][0] = zero; acc[i][1] = zero; }
    const __hip_bfloat16* w0 = Wt + (size_t)(colbase + l16) * D_HID + quad * 8;
    const __hip_bfloat16* w1 = w0 + 16 * D_HID;
#pragma unroll
    for (int ks = 0; ks < 8; ks++) {
        bf16x8 af[4];
#pragma unroll
        for (int rt = 0; rt < 4; rt++)
            af[rt] = *(const bf16x8*)&S[rt * 16 + l16][ks * 32 + quad * 8];
        bf16x8 b0 = *(const bf16x8*)(w0 + ks * 32);
        bf16x8 b1 = *(const bf16x8*)(w1 + ks * 32);
#pragma unroll
        for (int rt = 0; rt < 4; rt++) {
            acc[rt][0] = __builtin_amdgcn_mfma_f32_16x16x32_bf16(af[rt], b0, acc[rt][0], 0, 0, 0);
            acc[rt][1] = __builtin_amdgcn_mfma_f32_16x16x32_bf16(af[rt], b1, acc[rt][1], 0, 0, 0);
        }
    }
}

__global__ __launch_bounds__(512, 4) void mcat_mainF(const float* __restrict__ xsrc,
                          const __hip_bfloat16* __restrict__ w1t, const float* __restrict__ b1,
                          const __hip_bfloat16* __restrict__ wvt, const float* __restrict__ bv,
                          const __hip_bfloat16* __restrict__ wat, const float* __restrict__ ba,
                          const __hip_bfloat16* __restrict__ wbt, const float* __restrict__ bb,
                          const float* __restrict__ acw, const float* __restrict__ acb,
                          float* __restrict__ partials) {
    __shared__ __hip_bfloat16 Hs[ROWS][264];
    __shared__ __hip_bfloat16 Vs[ROWS][264];
    __shared__ float Apart[8][ROWS];
    __shared__ float ExpW[ROWS];
    const int tid  = threadIdx.x;
    const int wave = tid >> 6;
    const int lane = tid & 63;
    const int quad = lane >> 4;
    const int l16  = lane & 15;
    const int colbase = wave * 32;
    const int row0 = blockIdx.x * ROWS;
    f32x4 acc[4][2];
    f32x4 zero = {0.f, 0.f, 0.f, 0.f};
#pragma unroll
    for (int i = 0; i < 4; i++) { acc[i][0] = zero; acc[i][1] = zero; }
    const float* xf_base[4];
#pragma unroll
    for (int rt = 0; rt < 4; rt++) {
        int r = row0 + rt * 16 + l16;
        if (r > N_INST - 1) r = N_INST - 1;
        xf_base[rt] = xsrc + (size_t)r * D_IN + quad * 8;
    }
    const __hip_bfloat16* wb0 = w1t + (size_t)(colbase + l16) * D_IN + quad * 8;
    const __hip_bfloat16* wb1 = wb0 + 16 * D_IN;
    for (int kc = 0; kc < D_IN; kc += 32) {
        bf16x8 af[4];
#pragma unroll
        for (int rt = 0; rt < 4; rt++) af[rt] = load_cvt8(xf_base[rt] + kc);
        bf16x8 b0 = *(const bf16x8*)(wb0 + kc);
        bf16x8 b1 = *(const bf16x8*)(wb1 + kc);
#pragma unroll
        for (int rt = 0; rt < 4; rt++) {
            acc[rt][0] = __builtin_amdgcn_mfma_f32_16x16x32_bf16(af[rt], b0, acc[rt][0], 0, 0, 0);
            acc[rt][1] = __builtin_amdgcn_mfma_f32_16x16x32_bf16(af[rt], b1, acc[rt][1], 0, 0, 0);
        }
    }
#pragma unroll
    for (int ct = 0; ct < 2; ct++) {
        int col = colbase + ct * 16 + l16;
        float bias = b1[col];
#pragma unroll
        for (int rt = 0; rt < 4; rt++)
#pragma unroll
            for (int r = 0; r < 4; r++)
                Hs[rt * 16 + quad * 4 + r][col] = __float2bfloat16(fmaxf(acc[rt][ct][r] + bias, 0.f));
    }
    __syncthreads();
    gemm256_w8(Hs, wvt, colbase, quad, l16, acc);
#pragma unroll
    for (int ct = 0; ct < 2; ct++) {
        int col = colbase + ct * 16 + l16;
        float bias = bv[col];
#pragma unroll
        for (int rt = 0; rt < 4; rt++)
#pragma unroll
            for (int r = 0; r < 4; r++)
                Vs[rt * 16 + quad * 4 + r][col] = __float2bfloat16(acc[rt][ct][r] + bias);
    }
    __syncthreads();
    float a_reg[4][2][4];
    gemm256_w8(Vs, wat, colbase, quad, l16, acc);
#pragma unroll
    for (int ct = 0; ct < 2; ct++) {
        float bias = ba[colbase + ct * 16 + l16];
#pragma unroll
        for (int rt = 0; rt < 4; rt++)
#pragma unroll
            for (int r = 0; r < 4; r++)
                a_reg[rt][ct][r] = fast_tanh(acc[rt][ct][r] + bias);
    }
    gemm256_w8(Vs, wbt, colbase, quad, l16, acc);
    {
        float acw0 = acw[colbase + l16];
        float acw1 = acw[colbase + 16 + l16];
        float bias0 = bb[colbase + l16];
        float bias1 = bb[colbase + 16 + l16];
        float sp[4][4];
#pragma unroll
        for (int rt = 0; rt < 4; rt++)
#pragma unroll
            for (int r = 0; r < 4; r++) {
                float g0 = a_reg[rt][0][r] * fast_sigmoid(acc[rt][0][r] + bias0);
                float g1 = a_reg[rt][1][r] * fast_sigmoid(acc[rt][1][r] + bias1);
                sp[rt][r] = g0 * acw0 + g1 * acw1;
            }
#pragma unroll
        for (int off = 1; off < 16; off <<= 1)
#pragma unroll
            for (int rt = 0; rt < 4; rt++)
#pragma unroll
                for (int r = 0; r < 4; r++)
                    sp[rt][r] += __shfl_xor(sp[rt][r], off, 16);
        if (l16 == 0) {
#pragma unroll
            for (int rt = 0; rt < 4; rt++)
#pragma unroll
                for (int r = 0; r < 4; r++)
                    Apart[wave][rt * 16 + quad * 4 + r] = sp[rt][r];
        }
    }
    __syncthreads();
    if (tid < 64) {
        bool valid = (row0 + tid) < N_INST;
        float A = acb[0];
#pragma unroll
        for (int w = 0; w < 8; w++) A += Apart[w][tid];
        if (!valid) A = NEG_BIG;
        float m = A;
#pragma unroll
        for (int off = 32; off > 0; off >>= 1) m = fmaxf(m, __shfl_xor(m, off));
        float e = valid ? __expf(A - m) : 0.f;
        ExpW[tid] = e;
        float ssum = e;
#pragma unroll
        for (int off = 32; off > 0; off >>= 1) ssum += __shfl_xor(ssum, off);
        if (tid == 0) {
            partials[(size_t)blockIdx.x * PSTR + 0] = m;
            partials[(size_t)blockIdx.x * PSTR + 1] = ssum;
        }
    }
    __syncthreads();
    if (tid < 256) {
        float p = 0.f;
#pragma unroll 8
        for (int n = 0; n < 64; n++)
            p += ExpW[n] * __bfloat162float(Vs[n][tid]);
        partials[(size_t)blockIdx.x * PSTR + 2 + tid] = p;
    }
}

__global__ void mcat_fin_a(const float* __restrict__ p1, float* __restrict__ p2) {
    __shared__ float sm[1];
    int g = blockIdx.x, tid = threadIdx.x;
    int lo = g * CHUNK;
    int hi = lo + CHUNK; if (hi > NBLK) hi = NBLK;
    if (tid < 64) {
        float m = NEG_BIG;
        if (lo + tid < hi) m = p1[(size_t)(lo + tid) * PSTR];
#pragma unroll
        for (int off = 32; off > 0; off >>= 1) m = fmaxf(m, __shfl_xor(m, off));
        if (tid == 0) sm[0] = m;
    }
    __syncthreads();
    float M = sm[0];
    float p = 0.f, sacc = 0.f;
    for (int b = lo; b < hi; b++) {
        float sc = __expf(p1[(size_t)b * PSTR] - M);
        sacc += sc * p1[(size_t)b * PSTR + 1];
        p += sc * p1[(size_t)b * PSTR + 2 + tid];
    }
    if (tid == 0) {
        p2[(size_t)g * PSTR + 0] = M;
        p2[(size_t)g * PSTR + 1] = sacc;
    }
    p2[(size_t)g * PSTR + 2 + tid] = p;
}

__global__ void mcat_fin_b(const float* __restrict__ p2,
                           const float* __restrict__ c1w, const float* __restrict__ c1b,
                           const float* __restrict__ c2w, const float* __restrict__ c2b,
                           float* __restrict__ out) {
    __shared__ float sm[2];
    __shared__ float sc[NB2];
    __shared__ float pooled[D_HID];
    __shared__ float r1[D_CLS];
    int tid = threadIdx.x;
    if (tid < 64) {
        float m = p2[(size_t)tid * PSTR];
#pragma unroll
        for (int off = 32; off > 0; off >>= 1) m = fmaxf(m, __shfl_xor(m, off));
        if (tid == 0) sm[0] = m;
    }
    __syncthreads();
    float M = sm[0];
    if (tid < 64) {
        float s = __expf(p2[(size_t)tid * PSTR] - M);
        sc[tid] = s;
        float Ssum = s * p2[(size_t)tid * PSTR + 1];
#pragma unroll
        for (int off = 32; off > 0; off >>= 1) Ssum += __shfl_xor(Ssum, off);
        if (tid == 0) sm[1] = Ssum;
    }
    __syncthreads();
    float S = sm[1];
    float p = 0.f;
#pragma unroll 8
    for (int b = 0; b < NB2; b++)
        p += sc[b] * p2[(size_t)b * PSTR + 2 + tid];
    pooled[tid] = p / S;
    __syncthreads();
    if (tid < D_CLS) {
        float acc = c1b[tid];
#pragma unroll 8
        for (int d = 0; d < D_HID; d++)
            acc += pooled[d] * c1w[(size_t)d * D_CLS + tid];
        r1[tid] = fmaxf(acc, 0.f);
    }
    __syncthreads();
    if (tid < N_CLASSES) {
        float acc = c2b[tid];
#pragma unroll 8
        for (int j = 0; j < D_CLS; j++)
            acc += r1[j] * c2w[(size_t)j * N_CLASSES + tid];
        out[tid] = acc;
    }
}

extern "C" void kernel_launch(void* const* d_in, const int* in_sizes, int n_in,
                              void* d_out, int out_size, void* d_ws, size_t ws_size,
                              hipStream_t stream) {
    const float* xp  = (const float*)d_in[0];
    const float* w1  = (const float*)d_in[2];
    const float* b1  = (const float*)d_in[3];
    const float* wv  = (const float*)d_in[10];
    const float* bv  = (const float*)d_in[11];
    const float* wa  = (const float*)d_in[12];
    const float* ba  = (const float*)d_in[13];
    const float* wb  = (const float*)d_in[14];
    const float* bb  = (const float*)d_in[15];
    const float* acw = (const float*)d_in[16];
    const float* acb = (const float*)d_in[17];
    const float* c1w = (const float*)d_in[18];
    const float* c1b = (const float*)d_in[19];
    const float* c2w = (const float*)d_in[20];
    const float* c2b = (const float*)d_in[21];
    float* out = (float*)d_out;

    char* ws = (char*)d_ws;
    __hip_bfloat16* w1t = (__hip_bfloat16*)(ws + WS_W1T);
    __hip_bfloat16* wvt = (__hip_bfloat16*)(ws + WS_WVT);
    __hip_bfloat16* wat = (__hip_bfloat16*)(ws + WS_WAT);
    __hip_bfloat16* wbt = (__hip_bfloat16*)(ws + WS_WBT);

    const int use_main = (ws_size >= WS_NEED2) ? 1 : 0;
    hipLaunchKernelGGL(convert_weights, dim3(112), dim3(256), 0, stream,
                       w1, wv, wa, wb, w1t, wvt, wat, wbt, use_main);

    if (use_main) {
        unsigned int* counter = (unsigned int*)(ws + WS_CNT);
        float* p1 = (float*)(ws + WS_P1);
        __hip_bfloat16* h  = (__hip_bfloat16*)(ws + WS_H);
        hipMemsetAsync(counter, 0, 4, stream);
        hipLaunchKernelGGL(mcat_stage1i, dim3(G1I), dim3(256), 0, stream, xp, w1t, b1, h);
        hipLaunchKernelGGL(mcat_stage2, dim3(GB), dim3(512), 0, stream,
                           h, wvt, bv, wat, ba, wbt, bb, acw, acb, p1, counter,
                           c1w, c1b, c2w, c2b, out);
    } else {
        float* p1 = (float*)(ws + WS_P1F);
        float* p2 = (float*)(ws + WS_P2F);
        hipLaunchKernelGGL(mcat_mainF, dim3(NBLK), dim3(512), 0, stream,
                           xp, w1t, b1, wvt, bv, wat, ba, wbt, bb, acw, acb, p1);
        hipLaunchKernelGGL(mcat_fin_a, dim3(NB2), dim3(256), 0, stream, p1, p2);
        hipLaunchKernelGGL(mcat_fin_b, dim3(1), dim3(256), 0, stream,
                           p2, c1w, c1b, c2w, c2b, out);
    }
}